// Round 2
// baseline (14300.800 us; speedup 1.0000x reference)
//
#include <hip/hip_runtime.h>

#define DEV __device__ __forceinline__

constexpr int N = 50000;
constexpr int E = 800000;

// ---- workspace layout (float units) ----
constexpr int H0_OFF = 0;
constexpr int H_OFF  = H0_OFF + N*64;
constexpr int PC_OFF = H_OFF + N*64;
constexpr int PR_OFF = PC_OFF + N*128;
constexpr int MT_OFF = PR_OFF + N*128;
constexpr int MF_OFF = MT_OFF + N*64;
constexpr int UV_OFF = MF_OFF + N*64;
constexpr int AU_OFF = UV_OFF + N;
constexpr int LOSS_OFF = AU_OFF + N;     // 6 loss slots + pad + flag
constexpr int FLAG_OFF = LOSS_OFF + 7;
constexpr int WT2_OFF = LOSS_OFF + 8;    // 4096 f32 (pt_W2)
constexpr int WF2_OFF = WT2_OFF + 4096;  // 4096 (pf_W2)
constexpr int AT_OFF  = WF2_OFF + 4096;  // 192 (pt_W1 rows 128..130)
constexpr int AF_OFF  = AT_OFF + 192;    // 192
constexpr int BT1_OFF = AF_OFF + 192;    // 64
constexpr int BT2_OFF = BT1_OFF + 64;    // 64
constexpr int BF1_OFF = BT2_OFF + 64;    // 64
constexpr int BF2_OFF = BF1_OFF + 64;    // 64
constexpr int GS_OFF  = BF2_OFF + 64;    // 576: z192,z193,r192,r193,c192,c193,zb,rb,cb
constexpr int DW1_OFF = GS_OFF + 576;    // 4096
constexpr int DW2_OFF = DW1_OFF + 4096;  // 64
constexpr int DB1_OFF = DW2_OFF + 64;    // 64
constexpr int DB2_OFF = DB1_OFF + 64;    // 1 (+3 pad)
constexpr int EW1_OFF = DB2_OFF + 4;     // 64
constexpr int EB1_OFF = EW1_OFF + 64;    // 64
constexpr int EW2_OFF = EB1_OFF + 64;    // 4096
constexpr int EB2_OFF = EW2_OFF + 4096;  // 64
constexpr int GP_OFF  = EB2_OFF + 64;    // ushort8[4096] = 16384 float slots (gate pack)
constexpr int CH_OFF  = GP_OFF + 16384;  // 4096 f32 (corr_W rows 0..63)
constexpr int PT1_OFF = CH_OFF + 4096;   // 8192 f32 (pt_W1 rows 0..127)
constexpr int PF1_OFF = PT1_OFF + 8192;  // 8192 f32 (pf_W1 rows 0..127)
constexpr int WS_END  = PF1_OFF + 8192;  // ~25.75M floats ~= 103 MB

// prep job segments: WT2,WF2 (4096 ea), AT,AF (192), BT1,BT2,BF1,BF2 (64),
// GS 576, DW1 4096, DW2 64, DB1 64, DB2 1, EW1 64, EB1 64, EW2 4096, EB2 64,
// LOSS 6, CH 4096, PT1 8192, PF1 8192, GPpack 4096
constexpr int PREP_TOTAL = 4096+4096+192+192+64+64+64+64+576+4096+64+64+1+64+64+4096+64+6+4096+8192+8192+4096;

DEV float b2f(unsigned short u){ return __uint_as_float(((unsigned)u) << 16); }
DEV unsigned short f2b(float f){
    unsigned u = __float_as_uint(f);
    return (unsigned short)((u + 0x7fffu + ((u >> 16) & 1u)) >> 16);
}
DEV float blo(unsigned u){ return __uint_as_float(u << 16); }
DEV float bhi(unsigned u){ return __uint_as_float(u & 0xffff0000u); }
DEV float bcastf(float v, int k){
    return __uint_as_float(__builtin_amdgcn_readlane(__float_as_uint(v), k));
}
DEV float wave_sum(float v){
    #pragma unroll
    for (int off = 32; off > 0; off >>= 1) v += __shfl_xor(v, off, 64);
    return v;
}
// dtype-adaptive loads: isbf -> bf16 (ushort), else f32
DEV float ldv(const void* p, int i, bool isbf){
    return isbf ? b2f(((const unsigned short*)p)[i]) : ((const float*)p)[i];
}
DEV unsigned short ld16(const void* p, int i, bool isbf){
    return isbf ? ((const unsigned short*)p)[i] : f2b(((const float*)p)[i]);
}

struct WPtrs {
    const void *ptW1, *ptb1, *ptW2, *ptb2;
    const void *pfW1, *pfb1, *pfW2, *pfb2;
    const void *zkW, *zkb, *rkW, *rkb, *cW, *cb;
    const void *eW1, *eb1, *eW2, *eb2;
    const void *dW1, *db1, *dW2, *db2;
};

// ---- dtype detection: scan y as bf16; insane values => underlying f32 ----
__global__ __launch_bounds__(256) void detect_kernel(const void* y, float* __restrict__ ws){
    __shared__ int bad;
    if (threadIdx.x == 0) bad = 0;
    __syncthreads();
    const unsigned short* yy = (const unsigned short*)y;
    int mybad = 0;
    for (int i = threadIdx.x; i < 4096; i += 256){
        float v = b2f(yy[i]);
        if (!(v > -1.0e6f && v < 1.0e6f)) mybad = 1;   // catches NaN/Inf/huge
    }
    if (mybad) bad = 1;
    __syncthreads();
    if (threadIdx.x == 0) ws[FLAG_OFF] = bad ? 0.0f : 1.0f;
}

// ---- weight prep: (bf16|f32) -> f32 copies + gate ushort8 pack + zero loss ----
__global__ __launch_bounds__(256) void prep_kernel(WPtrs P, float* __restrict__ ws){
    int j = blockIdx.x * 256 + threadIdx.x;
    if (j >= PREP_TOTAL) return;
    bool isbf = ws[FLAG_OFF] > 0.5f;
    if (j < 4096){ ws[WT2_OFF+j] = ldv(P.ptW2, j, isbf); return; } j -= 4096;
    if (j < 4096){ ws[WF2_OFF+j] = ldv(P.pfW2, j, isbf); return; } j -= 4096;
    if (j < 192){ ws[AT_OFF+j] = ldv(P.ptW1, 128*64+j, isbf); return; } j -= 192;
    if (j < 192){ ws[AF_OFF+j] = ldv(P.pfW1, 128*64+j, isbf); return; } j -= 192;
    if (j < 64){ ws[BT1_OFF+j] = ldv(P.ptb1, j, isbf); return; } j -= 64;
    if (j < 64){ ws[BT2_OFF+j] = ldv(P.ptb2, j, isbf); return; } j -= 64;
    if (j < 64){ ws[BF1_OFF+j] = ldv(P.pfb1, j, isbf); return; } j -= 64;
    if (j < 64){ ws[BF2_OFF+j] = ldv(P.pfb2, j, isbf); return; } j -= 64;
    if (j < 576){
        int r = j >> 6, l = j & 63; float v;
        switch (r){
            case 0: v = ldv(P.zkW, 192*64+l, isbf); break;
            case 1: v = ldv(P.zkW, 193*64+l, isbf); break;
            case 2: v = ldv(P.rkW, 192*64+l, isbf); break;
            case 3: v = ldv(P.rkW, 193*64+l, isbf); break;
            case 4: v = ldv(P.cW,  192*64+l, isbf); break;
            case 5: v = ldv(P.cW,  193*64+l, isbf); break;
            case 6: v = ldv(P.zkb, l, isbf); break;
            case 7: v = ldv(P.rkb, l, isbf); break;
            default: v = ldv(P.cb, l, isbf); break;
        }
        ws[GS_OFF+j] = v; return;
    } j -= 576;
    if (j < 4096){ ws[DW1_OFF+j] = ldv(P.dW1, j, isbf); return; } j -= 4096;
    if (j < 64){ ws[DW2_OFF+j] = ldv(P.dW2, j, isbf); return; } j -= 64;
    if (j < 64){ ws[DB1_OFF+j] = ldv(P.db1, j, isbf); return; } j -= 64;
    if (j < 1){ ws[DB2_OFF] = ldv(P.db2, 0, isbf); return; } j -= 1;
    if (j < 64){ ws[EW1_OFF+j] = ldv(P.eW1, j, isbf); return; } j -= 64;
    if (j < 64){ ws[EB1_OFF+j] = ldv(P.eb1, j, isbf); return; } j -= 64;
    if (j < 4096){ ws[EW2_OFF+j] = ldv(P.eW2, j, isbf); return; } j -= 4096;
    if (j < 64){ ws[EB2_OFF+j] = ldv(P.eb2, j, isbf); return; } j -= 64;
    if (j < 6){ ws[LOSS_OFF+j] = 0.f; return; } j -= 6;
    if (j < 4096){ ws[CH_OFF+j] = ldv(P.cW, j, isbf); return; } j -= 4096;
    if (j < 8192){ ws[PT1_OFF+j] = ldv(P.ptW1, j, isbf); return; } j -= 8192;
    if (j < 8192){ ws[PF1_OFF+j] = ldv(P.pfW1, j, isbf); return; } j -= 8192;
    // gate pack: per (k,l): zH,rH | zMT,rMT | zMF,rMF | cMT,cMF  (bf16 pairs)
    {
        int k = j >> 6, l = j & 63;
        unsigned short* gp = (unsigned short*)(ws + GP_OFF) + (size_t)j * 8;
        gp[0] = ld16(P.zkW, k*64+l, isbf);        gp[1] = ld16(P.rkW, k*64+l, isbf);
        gp[2] = ld16(P.zkW, (64+k)*64+l, isbf);   gp[3] = ld16(P.rkW, (64+k)*64+l, isbf);
        gp[4] = ld16(P.zkW, (128+k)*64+l, isbf);  gp[5] = ld16(P.rkW, (128+k)*64+l, isbf);
        gp[6] = ld16(P.cW,  (64+k)*64+l, isbf);   gp[7] = ld16(P.cW,  (128+k)*64+l, isbf);
    }
}

// ---- encoder: H0 = relu(x*eW1 + eb1) @ eW2 + eb2 ; H = H0 ----
__global__ __launch_bounds__(256) void encode_init(const void* __restrict__ x,
                                                   float* __restrict__ ws){
    int idx = blockIdx.x * 256 + threadIdx.x;
    if (idx >= N*64) return;
    bool isbf = ws[FLAG_OFF] > 0.5f;
    int node = idx >> 6, f = idx & 63;
    float xv = ldv(x, node, isbf);
    float acc = ws[EB2_OFF+f];
    #pragma unroll
    for (int k = 0; k < 64; k++){
        float t = fmaxf(fmaf(xv, ws[EW1_OFF+k], ws[EB1_OFF+k]), 0.f);
        acc = fmaf(t, ws[EW2_OFF + k*64 + f], acc);
    }
    ws[H0_OFF+idx] = acc;
    ws[H_OFF+idx]  = acc;
}

// ---- per-node first-layer precompute + zero message buffers ----
__global__ __launch_bounds__(256) void node_pre(float* __restrict__ ws){
    int idx = blockIdx.x * 256 + threadIdx.x;
    if (idx >= N*64) return;
    int node = idx >> 6, f = idx & 63;
    const float* Hp = ws + H_OFF + (size_t)node*64;
    const float* T1 = ws + PT1_OFF;
    const float* F1 = ws + PF1_OFF;
    float a0 = 0.f, a1 = 0.f, a2 = 0.f, a3 = 0.f;
    #pragma unroll
    for (int k = 0; k < 64; k++){
        float hv = Hp[k];
        a0 = fmaf(hv, T1[k*64+f],      a0);  // PtA (gathered at col)
        a2 = fmaf(hv, T1[(64+k)*64+f], a2);  // PtB (gathered at row)
        a3 = fmaf(hv, F1[k*64+f],      a3);  // PfA (gathered at row)
        a1 = fmaf(hv, F1[(64+k)*64+f], a1);  // PfB (gathered at col)
    }
    int nb = node*128 + f;
    ws[PC_OFF+nb]     = a0;
    ws[PC_OFF+nb+64]  = a1;
    ws[PR_OFF+nb]     = a2;
    ws[PR_OFF+nb+64]  = a3;
    ws[MT_OFF+idx] = 0.f;
    ws[MF_OFF+idx] = 0.f;
}

// ---- fused edge messages: both MLPs, atomic scatter ----
__global__ __launch_bounds__(256) void edge_msgs(const int* __restrict__ ei,
                                                 const void* __restrict__ attr,
                                                 float* __restrict__ ws){
    int e = blockIdx.x * 256 + threadIdx.x;
    if (e >= E) return;
    bool isbf = ws[FLAG_OFF] > 0.5f;
    int r = ei[e], c = ei[E+e];
    float a0 = ldv(attr, 3*e, isbf), a1 = ldv(attr, 3*e+1, isbf), a2 = ldv(attr, 3*e+2, isbf);
    const float4* pc4 = (const float4*)(ws + PC_OFF) + (size_t)c*32;
    const float4* pr4 = (const float4*)(ws + PR_OFF) + (size_t)r*32;
    bool live = (r != c);

    float h[64];
    // ---- to-messages: h1 = relu(PtA[c] + PtB[r] + attr terms + b1)
    #pragma unroll
    for (int q = 0; q < 16; q++){
        float4 vc = pc4[q], vr = pr4[q];
        h[4*q+0] = vc.x + vr.x; h[4*q+1] = vc.y + vr.y;
        h[4*q+2] = vc.z + vr.z; h[4*q+3] = vc.w + vr.w;
    }
    #pragma unroll
    for (int k = 0; k < 64; k++){
        float t = h[k] + a0*ws[AT_OFF+k] + a1*ws[AT_OFF+64+k] + a2*ws[AT_OFF+128+k] + ws[BT1_OFF+k];
        h[k] = fmaxf(t, 0.f);
    }
    {
        float* MTp = ws + MT_OFF + (size_t)c*64;
        const float* W = ws + WT2_OFF;
        const float* B = ws + BT2_OFF;
        for (int lc = 0; lc < 8; lc++){
            float m[8];
            #pragma unroll
            for (int t = 0; t < 8; t++) m[t] = B[lc*8+t];
            #pragma unroll
            for (int k = 0; k < 64; k++){
                #pragma unroll
                for (int t = 0; t < 8; t++) m[t] = fmaf(h[k], W[k*64 + lc*8 + t], m[t]);
            }
            if (live){
                #pragma unroll
                for (int t = 0; t < 8; t++) atomicAdd(&MTp[lc*8+t], m[t]);
            }
        }
    }
    // ---- from-messages: h1 = relu(PfA[r] + PfB[c] + attr terms + b1)
    #pragma unroll
    for (int q = 0; q < 16; q++){
        float4 vc = pc4[16+q], vr = pr4[16+q];
        h[4*q+0] = vc.x + vr.x; h[4*q+1] = vc.y + vr.y;
        h[4*q+2] = vc.z + vr.z; h[4*q+3] = vc.w + vr.w;
    }
    #pragma unroll
    for (int k = 0; k < 64; k++){
        float t = h[k] + a0*ws[AF_OFF+k] + a1*ws[AF_OFF+64+k] + a2*ws[AF_OFF+128+k] + ws[BF1_OFF+k];
        h[k] = fmaxf(t, 0.f);
    }
    {
        float* MFp = ws + MF_OFF + (size_t)r*64;
        const float* W = ws + WF2_OFF;
        const float* B = ws + BF2_OFF;
        for (int lc = 0; lc < 8; lc++){
            float m[8];
            #pragma unroll
            for (int t = 0; t < 8; t++) m[t] = B[lc*8+t];
            #pragma unroll
            for (int k = 0; k < 64; k++){
                #pragma unroll
                for (int t = 0; t < 8; t++) m[t] = fmaf(h[k], W[k*64 + lc*8 + t], m[t]);
            }
            if (live){
                #pragma unroll
                for (int t = 0; t < 8; t++) atomicAdd(&MFp[lc*8+t], m[t]);
            }
        }
    }
}

// ---- gating + state update (wave per node, gate weights LDS-packed; 256 thr) ----
__global__ __launch_bounds__(256) void gate_kernel(const void* __restrict__ prb,
                                                   const int* __restrict__ tags,
                                                   float* __restrict__ ws){
    __shared__ uint4 sGP[4096];   // 64 KB
    const uint4* g = (const uint4*)(ws + GP_OFF);
    for (int i = threadIdx.x; i < 4096; i += 256) sGP[i] = g[i];
    __syncthreads();
    bool isbf = ws[FLAG_OFF] > 0.5f;
    int lane = threadIdx.x & 63;
    int wv = threadIdx.x >> 6;
    int gw = blockIdx.x * 4 + wv;
    int nwaves = gridDim.x * 4;
    const float* GS = ws + GS_OFF;
    const float* CH = ws + CH_OFF;
    for (int node = gw; node < N; node += nwaves){
        int base = node*64 + lane;
        float h  = ws[H_OFF+base];
        float mt = ws[MT_OFF+base];
        float mf = ws[MF_OFF+base];
        float p0 = ldv(prb, 2*node, isbf), p1 = ldv(prb, 2*node+1, isbf);
        float z  = GS[6*64+lane] + p0*GS[0*64+lane] + p1*GS[1*64+lane];
        float rr = GS[7*64+lane] + p0*GS[2*64+lane] + p1*GS[3*64+lane];
        float cp = GS[8*64+lane] + p0*GS[4*64+lane] + p1*GS[5*64+lane];
        #pragma unroll
        for (int k = 0; k < 64; k++){
            float hk = bcastf(h, k), mtk = bcastf(mt, k), mfk = bcastf(mf, k);
            uint4 q = sGP[k*64+lane];
            z  = fmaf(hk,  blo(q.x), z);  rr = fmaf(hk,  bhi(q.x), rr);
            z  = fmaf(mtk, blo(q.y), z);  rr = fmaf(mtk, bhi(q.y), rr);
            z  = fmaf(mfk, blo(q.z), z);  rr = fmaf(mfk, bhi(q.z), rr);
            cp = fmaf(mtk, blo(q.w), cp); cp = fmaf(mfk, bhi(q.w), cp);
        }
        float alpha = 1.f / (1.f + __expf(-z));
        float rst   = 1.f / (1.f + __expf(-rr));
        float gv = rst * h;
        #pragma unroll
        for (int k = 0; k < 64; k++) cp = fmaf(bcastf(gv, k), CH[k*64+lane], cp);
        float cr = tanhf(cp);
        float hn = fmaf(alpha, cr, h);
        if (tags[node] == 1) hn = ws[H0_OFF+base];
        ws[H_OFF+base] = hn;
    }
}

// ---- decoder + enc/auto losses (wave per node; 256 thr) ----
__global__ __launch_bounds__(256) void decode_loss(int step, float* __restrict__ ws){
    __shared__ float sdW1[4096];
    __shared__ float seW2[4096];
    __shared__ float sdW2[64], sdb1[64], seW1[64], seb1[64], seb2[64];
    for (int i = threadIdx.x; i < 4096; i += 256){
        sdW1[i] = ws[DW1_OFF+i];
        seW2[i] = ws[EW2_OFF+i];
    }
    if (threadIdx.x < 64){
        int l = threadIdx.x;
        sdW2[l] = ws[DW2_OFF+l]; sdb1[l] = ws[DB1_OFF+l];
        seW1[l] = ws[EW1_OFF+l]; seb1[l] = ws[EB1_OFF+l]; seb2[l] = ws[EB2_OFF+l];
    }
    __syncthreads();
    float db2v = ws[DB2_OFF];
    int lane = threadIdx.x & 63;
    int wv = threadIdx.x >> 6;
    int gw = blockIdx.x * 4 + wv;
    int nw = gridDim.x * 4;
    float encAcc = 0.f, autoAcc = 0.f;
    for (int node = gw; node < N; node += nw){
        float hn = ws[H_OFF + node*64 + lane];
        // U = relu(Hn@dW1+db1) @ dW2 + db2
        float acc = sdb1[lane];
        #pragma unroll
        for (int k = 0; k < 64; k++) acc = fmaf(bcastf(hn, k), sdW1[k*64+lane], acc);
        float h1 = fmaxf(acc, 0.f);
        float u = wave_sum(h1 * sdW2[lane]) + db2v;
        if (lane == 0){
            ws[UV_OFF+node] = u;
            ws[AU_OFF+node] = 0.f;
        }
        // E = encode(u)   (used by both enc_loss and autoenc_loss)
        float ea = seb2[lane];
        #pragma unroll
        for (int k = 0; k < 64; k++){
            float t = fmaxf(fmaf(u, seW1[k], seb1[k]), 0.f);
            ea = fmaf(t, seW2[k*64+lane], ea);
        }
        float d = ea - hn;
        encAcc += d*d;
        // D2 = decode(E)
        float acc2 = sdb1[lane];
        #pragma unroll
        for (int k = 0; k < 64; k++) acc2 = fmaf(bcastf(ea, k), sdW1[k*64+lane], acc2);
        float h2 = fmaxf(acc2, 0.f);
        float d2 = wave_sum(h2 * sdW2[lane]) + db2v;
        float ad = d2 - u;
        if (lane == 0) autoAcc += ad*ad;
    }
    encAcc = wave_sum(encAcc);
    if (lane == 0){
        atomicAdd(&ws[LOSS_OFF + step*3 + 1], encAcc);
        atomicAdd(&ws[LOSS_OFF + step*3 + 2], autoAcc);
    }
}

// ---- residual: Au = segsum(a_ij * U[col], row) (self-loops INCLUDED) ----
__global__ __launch_bounds__(256) void residual_edge(const int* __restrict__ ei,
                                                     const void* __restrict__ aij,
                                                     float* __restrict__ ws){
    int e = blockIdx.x * 256 + threadIdx.x;
    if (e >= E) return;
    bool isbf = ws[FLAG_OFF] > 0.5f;
    int r = ei[e], c = ei[E+e];
    atomicAdd(&ws[AU_OFF+r], ldv(aij, e, isbf) * ws[UV_OFF+c]);
}

__global__ __launch_bounds__(256) void residual_reduce(int step, const void* __restrict__ y,
                                                       float* __restrict__ ws){
    int i = blockIdx.x * 256 + threadIdx.x;
    bool isbf = ws[FLAG_OFF] > 0.5f;
    float s = 0.f;
    if (i < N){
        float d = ws[AU_OFF+i] - ldv(y, i, isbf);
        s = d*d;
    }
    s = wave_sum(s);
    if ((threadIdx.x & 63) == 0) atomicAdd(&ws[LOSS_OFF + step*3], s);
}

// ---- output writer: U (N elems) + total (1 elem), dtype-branched ----
__global__ __launch_bounds__(256) void write_out(void* __restrict__ outp,
                                                 const float* __restrict__ ws){
    int i = blockIdx.x * 256 + threadIdx.x;
    if (i > N) return;
    bool isbf = ws[FLAG_OFF] > 0.5f;
    float v;
    if (i < N){
        v = ws[UV_OFF+i];
    } else {
        const float* L = ws + LOSS_OFF;
        float inv = 1.f / (float)N, invl = 1.f / ((float)N * 64.f);
        v = 0.9f*L[0]*inv + L[1]*invl + L[2]*inv
          +      L[3]*inv + L[4]*invl + L[5]*inv;
    }
    if (isbf) ((unsigned short*)outp)[i] = f2b(v);
    else      ((float*)outp)[i] = v;
}

extern "C" void kernel_launch(void* const* d_in, const int* in_sizes, int n_in,
                              void* d_out, int out_size, void* d_ws, size_t ws_size,
                              hipStream_t stream){
    const void* x    = d_in[0];
    const void* y    = d_in[2];
    const int* tags  = (const int*)d_in[3];
    const int* ei    = (const int*)d_in[4];
    const void* attr = d_in[5];
    const void* aij  = d_in[6];
    const void* prb  = d_in[7];
    WPtrs P;
    P.ptW1 = d_in[8];  P.ptb1 = d_in[9];  P.ptW2 = d_in[10]; P.ptb2 = d_in[11];
    P.pfW1 = d_in[12]; P.pfb1 = d_in[13]; P.pfW2 = d_in[14]; P.pfb2 = d_in[15];
    P.zkW  = d_in[16]; P.zkb  = d_in[17]; P.rkW  = d_in[18]; P.rkb  = d_in[19];
    P.cW   = d_in[20]; P.cb   = d_in[21];
    P.eW1  = d_in[22]; P.eb1  = d_in[23]; P.eW2  = d_in[24]; P.eb2  = d_in[25];
    P.dW1  = d_in[26]; P.db1  = d_in[27]; P.dW2  = d_in[28]; P.db2  = d_in[29];
    float* ws = (float*)d_ws;

    detect_kernel<<<1, 256, 0, stream>>>(y, ws);
    prep_kernel<<<(PREP_TOTAL + 255)/256, 256, 0, stream>>>(P, ws);
    encode_init<<<(N*64)/256, 256, 0, stream>>>(x, ws);
    for (int step = 0; step < 2; step++){
        node_pre<<<(N*64)/256, 256, 0, stream>>>(ws);
        edge_msgs<<<E/256, 256, 0, stream>>>(ei, attr, ws);
        gate_kernel<<<512, 256, 0, stream>>>(prb, tags, ws);
        decode_loss<<<256, 256, 0, stream>>>(step, ws);
        residual_edge<<<E/256, 256, 0, stream>>>(ei, aij, ws);
        residual_reduce<<<(N + 255)/256, 256, 0, stream>>>(step, y, ws);
    }
    write_out<<<(N + 256)/256, 256, 0, stream>>>(d_out, ws);
}

// Round 3
// 4892.759 us; speedup vs baseline: 2.9228x; 2.9228x over previous
//
#include <hip/hip_runtime.h>

#define DEV __device__ __forceinline__

constexpr int N = 50000;
constexpr int E = 800000;

// ---- workspace layout (4-byte units) ----
constexpr int H0_OFF  = 0;                    // N*64
constexpr int H_OFF   = H0_OFF + N*64;        // N*64
constexpr int PGB_OFF = H_OFF + N*64;         // N*128: per node [PtB(64) | PfB(64)]
constexpr int MT_OFF  = PGB_OFF + N*128;      // N*64
constexpr int MF_OFF  = MT_OFF + N*64;        // N*64
constexpr int UV_OFF  = MF_OFF + N*64;        // N
constexpr int LOSS_OFF = UV_OFF + N;          // 6 loss slots + pad + flag
constexpr int FLAG_OFF = LOSS_OFF + 7;
constexpr int WT2_OFF = LOSS_OFF + 8;         // 4096 (pt_W2 f32)
constexpr int WF2_OFF = WT2_OFF + 4096;       // 4096
constexpr int AT_OFF  = WF2_OFF + 4096;       // 192 (pt_W1 rows 128..130)
constexpr int AF_OFF  = AT_OFF + 192;         // 192
constexpr int BT1_OFF = AF_OFF + 192;         // 64
constexpr int BT2_OFF = BT1_OFF + 64;         // 64
constexpr int BF1_OFF = BT2_OFF + 64;         // 64
constexpr int BF2_OFF = BF1_OFF + 64;         // 64
constexpr int GS_OFF  = BF2_OFF + 64;         // 576
constexpr int DW1_OFF = GS_OFF + 576;         // 4096
constexpr int DW2_OFF = DW1_OFF + 4096;       // 64
constexpr int DB1_OFF = DW2_OFF + 64;         // 64
constexpr int DB2_OFF = DB1_OFF + 64;         // 1 (+3 pad)
constexpr int EW1_OFF = DB2_OFF + 4;          // 64
constexpr int EB1_OFF = EW1_OFF + 64;         // 64
constexpr int EW2_OFF = EB1_OFF + 64;         // 4096
constexpr int EB2_OFF = EW2_OFF + 4096;       // 64
constexpr int GP_OFF  = EB2_OFF + 64;         // 16384 (gate ushort8 pack)
constexpr int CH_OFF  = GP_OFF + 16384;       // 4096 (corr_W rows 0..63)
constexpr int PT1_OFF = CH_OFF + 4096;        // 8192 (pt_W1 rows 0..127, f32)
constexpr int PF1_OFF = PT1_OFF + 8192;       // 8192
constexpr int FEND    = PF1_OFF + 8192;
// int region (CSR)
constexpr int CP_OFF   = FEND;                // colPtr N+1
constexpr int RP_OFF   = CP_OFF + N + 1;      // rowPtr N+1
constexpr int CF_OFF   = RP_OFF + N + 1;      // colFill N
constexpr int RF_OFF   = CF_OFF + N;          // rowFill N
constexpr int CDEG_OFF = RF_OFF + N;          // N
constexpr int RDEG_OFF = CDEG_OFF + N;        // N
constexpr int CIDX_OFF = RDEG_OFF + N;        // E
constexpr int RIDX_OFF = CIDX_OFF + E;        // E
constexpr int WS_END   = RIDX_OFF + E;        // ~21.2M * 4B = ~85 MB

constexpr int PREP_TOTAL = 4096+4096+192+192+64+64+64+64+576+4096+64+64+1+64+64+4096+64+6+4096+8192+8192+4096;

DEV float b2f(unsigned short u){ return __uint_as_float(((unsigned)u) << 16); }
DEV unsigned short f2b(float f){
    unsigned u = __float_as_uint(f);
    return (unsigned short)((u + 0x7fffu + ((u >> 16) & 1u)) >> 16);
}
DEV float blo(unsigned u){ return __uint_as_float(u << 16); }
DEV float bhi(unsigned u){ return __uint_as_float(u & 0xffff0000u); }
DEV float bcastf(float v, int k){
    return __uint_as_float(__builtin_amdgcn_readlane(__float_as_uint(v), k));
}
DEV int bcasti(int v, int k){ return __builtin_amdgcn_readlane(v, k); }
DEV float wave_sum(float v){
    #pragma unroll
    for (int off = 32; off > 0; off >>= 1) v += __shfl_xor(v, off, 64);
    return v;
}
DEV float ldv(const void* p, int i, bool isbf){
    return isbf ? b2f(((const unsigned short*)p)[i]) : ((const float*)p)[i];
}
DEV unsigned short ld16(const void* p, int i, bool isbf){
    return isbf ? ((const unsigned short*)p)[i] : f2b(((const float*)p)[i]);
}

struct WPtrs {
    const void *ptW1, *ptb1, *ptW2, *ptb2;
    const void *pfW1, *pfb1, *pfW2, *pfb2;
    const void *zkW, *zkb, *rkW, *rkb, *cW, *cb;
    const void *eW1, *eb1, *eW2, *eb2;
    const void *dW1, *db1, *dW2, *db2;
};

// ---- dtype detection ----
__global__ __launch_bounds__(256) void detect_kernel(const void* y, float* __restrict__ ws){
    __shared__ int bad;
    if (threadIdx.x == 0) bad = 0;
    __syncthreads();
    const unsigned short* yy = (const unsigned short*)y;
    int mybad = 0;
    for (int i = threadIdx.x; i < 4096; i += 256){
        float v = b2f(yy[i]);
        if (!(v > -1.0e6f && v < 1.0e6f)) mybad = 1;
    }
    if (mybad) bad = 1;
    __syncthreads();
    if (threadIdx.x == 0) ws[FLAG_OFF] = bad ? 0.0f : 1.0f;
}

// ---- weight prep ----
__global__ __launch_bounds__(256) void prep_kernel(WPtrs P, float* __restrict__ ws){
    int j = blockIdx.x * 256 + threadIdx.x;
    if (j >= PREP_TOTAL) return;
    bool isbf = ws[FLAG_OFF] > 0.5f;
    if (j < 4096){ ws[WT2_OFF+j] = ldv(P.ptW2, j, isbf); return; } j -= 4096;
    if (j < 4096){ ws[WF2_OFF+j] = ldv(P.pfW2, j, isbf); return; } j -= 4096;
    if (j < 192){ ws[AT_OFF+j] = ldv(P.ptW1, 128*64+j, isbf); return; } j -= 192;
    if (j < 192){ ws[AF_OFF+j] = ldv(P.pfW1, 128*64+j, isbf); return; } j -= 192;
    if (j < 64){ ws[BT1_OFF+j] = ldv(P.ptb1, j, isbf); return; } j -= 64;
    if (j < 64){ ws[BT2_OFF+j] = ldv(P.ptb2, j, isbf); return; } j -= 64;
    if (j < 64){ ws[BF1_OFF+j] = ldv(P.pfb1, j, isbf); return; } j -= 64;
    if (j < 64){ ws[BF2_OFF+j] = ldv(P.pfb2, j, isbf); return; } j -= 64;
    if (j < 576){
        int r = j >> 6, l = j & 63; float v;
        switch (r){
            case 0: v = ldv(P.zkW, 192*64+l, isbf); break;
            case 1: v = ldv(P.zkW, 193*64+l, isbf); break;
            case 2: v = ldv(P.rkW, 192*64+l, isbf); break;
            case 3: v = ldv(P.rkW, 193*64+l, isbf); break;
            case 4: v = ldv(P.cW,  192*64+l, isbf); break;
            case 5: v = ldv(P.cW,  193*64+l, isbf); break;
            case 6: v = ldv(P.zkb, l, isbf); break;
            case 7: v = ldv(P.rkb, l, isbf); break;
            default: v = ldv(P.cb, l, isbf); break;
        }
        ws[GS_OFF+j] = v; return;
    } j -= 576;
    if (j < 4096){ ws[DW1_OFF+j] = ldv(P.dW1, j, isbf); return; } j -= 4096;
    if (j < 64){ ws[DW2_OFF+j] = ldv(P.dW2, j, isbf); return; } j -= 64;
    if (j < 64){ ws[DB1_OFF+j] = ldv(P.db1, j, isbf); return; } j -= 64;
    if (j < 1){ ws[DB2_OFF] = ldv(P.db2, 0, isbf); return; } j -= 1;
    if (j < 64){ ws[EW1_OFF+j] = ldv(P.eW1, j, isbf); return; } j -= 64;
    if (j < 64){ ws[EB1_OFF+j] = ldv(P.eb1, j, isbf); return; } j -= 64;
    if (j < 4096){ ws[EW2_OFF+j] = ldv(P.eW2, j, isbf); return; } j -= 4096;
    if (j < 64){ ws[EB2_OFF+j] = ldv(P.eb2, j, isbf); return; } j -= 64;
    if (j < 6){ ws[LOSS_OFF+j] = 0.f; return; } j -= 6;
    if (j < 4096){ ws[CH_OFF+j] = ldv(P.cW, j, isbf); return; } j -= 4096;
    if (j < 8192){ ws[PT1_OFF+j] = ldv(P.ptW1, j, isbf); return; } j -= 8192;
    if (j < 8192){ ws[PF1_OFF+j] = ldv(P.pfW1, j, isbf); return; } j -= 8192;
    {   // gate pack: per (k,l): zH,rH | zMT,rMT | zMF,rMF | cMT,cMF (bf16)
        int k = j >> 6, l = j & 63;
        unsigned short* gp = (unsigned short*)(ws + GP_OFF) + (size_t)j * 8;
        gp[0] = ld16(P.zkW, k*64+l, isbf);        gp[1] = ld16(P.rkW, k*64+l, isbf);
        gp[2] = ld16(P.zkW, (64+k)*64+l, isbf);   gp[3] = ld16(P.rkW, (64+k)*64+l, isbf);
        gp[4] = ld16(P.zkW, (128+k)*64+l, isbf);  gp[5] = ld16(P.rkW, (128+k)*64+l, isbf);
        gp[6] = ld16(P.cW,  (64+k)*64+l, isbf);   gp[7] = ld16(P.cW,  (128+k)*64+l, isbf);
    }
}

// ---- CSR build ----
__global__ __launch_bounds__(256) void zero_deg(int* __restrict__ wsI){
    int i = blockIdx.x * 256 + threadIdx.x;
    if (i < N){ wsI[CDEG_OFF+i] = 0; wsI[RDEG_OFF+i] = 0; }
}
__global__ __launch_bounds__(256) void hist_kernel(const int* __restrict__ ei, int* __restrict__ wsI){
    int e = blockIdx.x * 256 + threadIdx.x;
    if (e >= E) return;
    atomicAdd(&wsI[RDEG_OFF + ei[e]], 1);
    atomicAdd(&wsI[CDEG_OFF + ei[E+e]], 1);
}
__global__ __launch_bounds__(256) void scan_kernel(const int* __restrict__ deg,
                                                   int* __restrict__ ptr,
                                                   int* __restrict__ fill){
    __shared__ int sh[256];
    __shared__ int carry;
    if (threadIdx.x == 0) carry = 0;
    __syncthreads();
    for (int base = 0; base < N; base += 256){
        int i = base + threadIdx.x;
        int v = (i < N) ? deg[i] : 0;
        sh[threadIdx.x] = v;
        __syncthreads();
        #pragma unroll
        for (int off = 1; off < 256; off <<= 1){
            int t = (threadIdx.x >= off) ? sh[threadIdx.x - off] : 0;
            __syncthreads();
            sh[threadIdx.x] += t;
            __syncthreads();
        }
        int excl = sh[threadIdx.x] - v;
        if (i < N){ ptr[i] = carry + excl; fill[i] = carry + excl; }
        __syncthreads();
        if (threadIdx.x == 0) carry += sh[255];
        __syncthreads();
    }
    if (threadIdx.x == 0) ptr[N] = carry;
}
__global__ __launch_bounds__(256) void scatter_kernel(const int* __restrict__ ei, int* __restrict__ wsI){
    int e = blockIdx.x * 256 + threadIdx.x;
    if (e >= E) return;
    int r = ei[e], c = ei[E+e];
    int q = atomicAdd(&wsI[RF_OFF + r], 1);
    wsI[RIDX_OFF + q] = e;
    int p = atomicAdd(&wsI[CF_OFF + c], 1);
    wsI[CIDX_OFF + p] = e;
}

// ---- encoder ----
__global__ __launch_bounds__(256) void encode_init(const void* __restrict__ x,
                                                   float* __restrict__ ws){
    int idx = blockIdx.x * 256 + threadIdx.x;
    if (idx >= N*64) return;
    bool isbf = ws[FLAG_OFF] > 0.5f;
    int node = idx >> 6, f = idx & 63;
    float xv = ldv(x, node, isbf);
    float acc = ws[EB2_OFF+f];
    #pragma unroll
    for (int k = 0; k < 64; k++){
        float t = fmaxf(fmaf(xv, ws[EW1_OFF+k], ws[EB1_OFF+k]), 0.f);
        acc = fmaf(t, ws[EW2_OFF + k*64 + f], acc);
    }
    ws[H0_OFF+idx] = acc;
    ws[H_OFF+idx]  = acc;
}

// ---- per-node gathered-side first-layer parts: PtB, PfB ----
__global__ __launch_bounds__(256) void node_pre(float* __restrict__ ws){
    int idx = blockIdx.x * 256 + threadIdx.x;
    if (idx >= N*64) return;
    int node = idx >> 6, f = idx & 63;
    const float* Hp = ws + H_OFF + (size_t)node*64;
    const float* T1 = ws + PT1_OFF;
    const float* F1 = ws + PF1_OFF;
    float bt = 0.f, bf = 0.f;
    #pragma unroll
    for (int k = 0; k < 64; k++){
        float hv = Hp[k];
        bt = fmaf(hv, T1[(64+k)*64+f], bt);   // PtB (gathered at row in mt)
        bf = fmaf(hv, F1[(64+k)*64+f], bf);   // PfB (gathered at col in mf)
    }
    ws[PGB_OFF + (size_t)node*128 + f]      = bt;
    ws[PGB_OFF + (size_t)node*128 + 64 + f] = bf;
}

// ---- CSR message gather: wave per node, lane = feature ----
// out[node] = (sum_live relu(W1c'H[node] + PGBpart[other] + attr@A3 + b1)) @ W2 + cnt*b2
__global__ __launch_bounds__(256) void gather_msgs(const int* __restrict__ csrPtr,
                                                   const int* __restrict__ csrIdx,
                                                   const int* __restrict__ other,
                                                   const void* __restrict__ attr,
                                                   const float* __restrict__ W1,
                                                   const float* __restrict__ A3,
                                                   const float* __restrict__ b1,
                                                   const float* __restrict__ W2,
                                                   const float* __restrict__ b2,
                                                   const float* __restrict__ pgb,
                                                   float* __restrict__ outbuf,
                                                   const float* __restrict__ Hbuf,
                                                   const float* __restrict__ flagp){
    bool isbf = *flagp > 0.5f;
    int lane = threadIdx.x & 63;
    int wv = threadIdx.x >> 6;
    float W1c[64], W2c[64];
    #pragma unroll
    for (int k = 0; k < 64; k++) W1c[k] = W1[k*64 + lane];
    #pragma unroll
    for (int k = 0; k < 64; k++) W2c[k] = W2[k*64 + lane];
    float A0 = A3[lane], A1 = A3[64+lane], A2 = A3[128+lane];
    float B1 = b1[lane], B2 = b2[lane];
    int gw = blockIdx.x * 4 + wv;
    int nw = gridDim.x * 4;
    for (int node = gw; node < N; node += nw){
        float h = Hbuf[(size_t)node*64 + lane];
        float pa = 0.f;
        #pragma unroll
        for (int k = 0; k < 64; k++) pa = fmaf(bcastf(h, k), W1c[k], pa);
        float hs = 0.f;
        int cnt = 0;
        int beg = csrPtr[node], end = csrPtr[node+1];
        for (int base = beg; base < end; base += 64){
            int mcnt = end - base; if (mcnt > 64) mcnt = 64;
            int eL = 0, oL = 0;
            float a0L = 0.f, a1L = 0.f, a2L = 0.f;
            if (lane < mcnt){
                eL = csrIdx[base + lane];
                oL = other[eL];
                a0L = ldv(attr, 3*eL,   isbf);
                a1L = ldv(attr, 3*eL+1, isbf);
                a2L = ldv(attr, 3*eL+2, isbf);
            }
            for (int t = 0; t < mcnt; t++){
                int o = bcasti(oL, t);
                if (o == node) continue;
                float a0 = bcastf(a0L, t), a1 = bcastf(a1L, t), a2 = bcastf(a2L, t);
                float pb = pgb[(size_t)o*128 + lane];
                float hv = pa + pb + a0*A0 + a1*A1 + a2*A2 + B1;
                hs += fmaxf(hv, 0.f);
                cnt++;
            }
        }
        float m = (float)cnt * B2;
        #pragma unroll
        for (int k = 0; k < 64; k++) m = fmaf(bcastf(hs, k), W2c[k], m);
        outbuf[(size_t)node*64 + lane] = m;
    }
}

// ---- gating + state update ----
__global__ __launch_bounds__(256) void gate_kernel(const void* __restrict__ prb,
                                                   const int* __restrict__ tags,
                                                   float* __restrict__ ws){
    __shared__ uint4 sGP[4096];   // 64 KB
    const uint4* g = (const uint4*)(ws + GP_OFF);
    for (int i = threadIdx.x; i < 4096; i += 256) sGP[i] = g[i];
    __syncthreads();
    bool isbf = ws[FLAG_OFF] > 0.5f;
    int lane = threadIdx.x & 63;
    int wv = threadIdx.x >> 6;
    int gw = blockIdx.x * 4 + wv;
    int nwaves = gridDim.x * 4;
    const float* GS = ws + GS_OFF;
    const float* CH = ws + CH_OFF;
    for (int node = gw; node < N; node += nwaves){
        int base = node*64 + lane;
        float h  = ws[H_OFF+base];
        float mt = ws[MT_OFF+base];
        float mf = ws[MF_OFF+base];
        float p0 = ldv(prb, 2*node, isbf), p1 = ldv(prb, 2*node+1, isbf);
        float z  = GS[6*64+lane] + p0*GS[0*64+lane] + p1*GS[1*64+lane];
        float rr = GS[7*64+lane] + p0*GS[2*64+lane] + p1*GS[3*64+lane];
        float cp = GS[8*64+lane] + p0*GS[4*64+lane] + p1*GS[5*64+lane];
        #pragma unroll
        for (int k = 0; k < 64; k++){
            float hk = bcastf(h, k), mtk = bcastf(mt, k), mfk = bcastf(mf, k);
            uint4 q = sGP[k*64+lane];
            z  = fmaf(hk,  blo(q.x), z);  rr = fmaf(hk,  bhi(q.x), rr);
            z  = fmaf(mtk, blo(q.y), z);  rr = fmaf(mtk, bhi(q.y), rr);
            z  = fmaf(mfk, blo(q.z), z);  rr = fmaf(mfk, bhi(q.z), rr);
            cp = fmaf(mtk, blo(q.w), cp); cp = fmaf(mfk, bhi(q.w), cp);
        }
        float alpha = 1.f / (1.f + __expf(-z));
        float rst   = 1.f / (1.f + __expf(-rr));
        float gv = rst * h;
        #pragma unroll
        for (int k = 0; k < 64; k++) cp = fmaf(bcastf(gv, k), CH[k*64+lane], cp);
        float cr = tanhf(cp);
        float hn = fmaf(alpha, cr, h);
        if (tags[node] == 1) hn = ws[H0_OFF+base];
        ws[H_OFF+base] = hn;
    }
}

// ---- decoder + enc/auto losses ----
__global__ __launch_bounds__(256) void decode_loss(int step, float* __restrict__ ws){
    __shared__ float sdW1[4096];
    __shared__ float seW2[4096];
    __shared__ float sdW2[64], sdb1[64], seW1[64], seb1[64], seb2[64];
    for (int i = threadIdx.x; i < 4096; i += 256){
        sdW1[i] = ws[DW1_OFF+i];
        seW2[i] = ws[EW2_OFF+i];
    }
    if (threadIdx.x < 64){
        int l = threadIdx.x;
        sdW2[l] = ws[DW2_OFF+l]; sdb1[l] = ws[DB1_OFF+l];
        seW1[l] = ws[EW1_OFF+l]; seb1[l] = ws[EB1_OFF+l]; seb2[l] = ws[EB2_OFF+l];
    }
    __syncthreads();
    float db2v = ws[DB2_OFF];
    int lane = threadIdx.x & 63;
    int wv = threadIdx.x >> 6;
    int gw = blockIdx.x * 4 + wv;
    int nw = gridDim.x * 4;
    float encAcc = 0.f, autoAcc = 0.f;
    for (int node = gw; node < N; node += nw){
        float hn = ws[H_OFF + node*64 + lane];
        float acc = sdb1[lane];
        #pragma unroll
        for (int k = 0; k < 64; k++) acc = fmaf(bcastf(hn, k), sdW1[k*64+lane], acc);
        float h1 = fmaxf(acc, 0.f);
        float u = wave_sum(h1 * sdW2[lane]) + db2v;
        if (lane == 0) ws[UV_OFF+node] = u;
        float ea = seb2[lane];
        #pragma unroll
        for (int k = 0; k < 64; k++){
            float t = fmaxf(fmaf(u, seW1[k], seb1[k]), 0.f);
            ea = fmaf(t, seW2[k*64+lane], ea);
        }
        float d = ea - hn;
        encAcc += d*d;
        float acc2 = sdb1[lane];
        #pragma unroll
        for (int k = 0; k < 64; k++) acc2 = fmaf(bcastf(ea, k), sdW1[k*64+lane], acc2);
        float h2 = fmaxf(acc2, 0.f);
        float d2 = wave_sum(h2 * sdW2[lane]) + db2v;
        float ad = d2 - u;
        if (lane == 0) autoAcc += ad*ad;
    }
    encAcc = wave_sum(encAcc);
    if (lane == 0){
        atomicAdd(&ws[LOSS_OFF + step*3 + 1], encAcc);
        atomicAdd(&ws[LOSS_OFF + step*3 + 2], autoAcc);
    }
}

// ---- residual via row-CSR gather (self-loops INCLUDED) ----
__global__ __launch_bounds__(256) void resid_csr(int step, const int* __restrict__ ei,
                                                 const void* __restrict__ aij,
                                                 const void* __restrict__ y,
                                                 float* __restrict__ ws){
    const int* wsI = (const int*)ws;
    int i = blockIdx.x * 256 + threadIdx.x;
    bool isbf = ws[FLAG_OFF] > 0.5f;
    float s = 0.f;
    if (i < N){
        float acc = 0.f;
        int beg = wsI[RP_OFF+i], end = wsI[RP_OFF+i+1];
        for (int j = beg; j < end; j++){
            int e = wsI[RIDX_OFF+j];
            int c = ei[E+e];
            acc = fmaf(ldv(aij, e, isbf), ws[UV_OFF+c], acc);
        }
        float d = acc - ldv(y, i, isbf);
        s = d*d;
    }
    s = wave_sum(s);
    if ((threadIdx.x & 63) == 0) atomicAdd(&ws[LOSS_OFF + step*3], s);
}

// ---- output writer ----
__global__ __launch_bounds__(256) void write_out(void* __restrict__ outp,
                                                 const float* __restrict__ ws){
    int i = blockIdx.x * 256 + threadIdx.x;
    if (i > N) return;
    bool isbf = ws[FLAG_OFF] > 0.5f;
    float v;
    if (i < N){
        v = ws[UV_OFF+i];
    } else {
        const float* L = ws + LOSS_OFF;
        float inv = 1.f / (float)N, invl = 1.f / ((float)N * 64.f);
        v = 0.9f*L[0]*inv + L[1]*invl + L[2]*inv
          +      L[3]*inv + L[4]*invl + L[5]*inv;
    }
    if (isbf) ((unsigned short*)outp)[i] = f2b(v);
    else      ((float*)outp)[i] = v;
}

extern "C" void kernel_launch(void* const* d_in, const int* in_sizes, int n_in,
                              void* d_out, int out_size, void* d_ws, size_t ws_size,
                              hipStream_t stream){
    const void* x    = d_in[0];
    const void* y    = d_in[2];
    const int* tags  = (const int*)d_in[3];
    const int* ei    = (const int*)d_in[4];
    const void* attr = d_in[5];
    const void* aij  = d_in[6];
    const void* prb  = d_in[7];
    WPtrs P;
    P.ptW1 = d_in[8];  P.ptb1 = d_in[9];  P.ptW2 = d_in[10]; P.ptb2 = d_in[11];
    P.pfW1 = d_in[12]; P.pfb1 = d_in[13]; P.pfW2 = d_in[14]; P.pfb2 = d_in[15];
    P.zkW  = d_in[16]; P.zkb  = d_in[17]; P.rkW  = d_in[18]; P.rkb  = d_in[19];
    P.cW   = d_in[20]; P.cb   = d_in[21];
    P.eW1  = d_in[22]; P.eb1  = d_in[23]; P.eW2  = d_in[24]; P.eb2  = d_in[25];
    P.dW1  = d_in[26]; P.db1  = d_in[27]; P.dW2  = d_in[28]; P.db2  = d_in[29];
    float* ws = (float*)d_ws;
    int* wsI = (int*)d_ws;

    detect_kernel<<<1, 256, 0, stream>>>(y, ws);
    prep_kernel<<<(PREP_TOTAL + 255)/256, 256, 0, stream>>>(P, ws);
    // CSR build (once per call; edge_index constant within a call)
    zero_deg<<<(N + 255)/256, 256, 0, stream>>>(wsI);
    hist_kernel<<<E/256, 256, 0, stream>>>(ei, wsI);
    scan_kernel<<<1, 256, 0, stream>>>(wsI + CDEG_OFF, wsI + CP_OFF, wsI + CF_OFF);
    scan_kernel<<<1, 256, 0, stream>>>(wsI + RDEG_OFF, wsI + RP_OFF, wsI + RF_OFF);
    scatter_kernel<<<E/256, 256, 0, stream>>>(ei, wsI);
    encode_init<<<(N*64)/256, 256, 0, stream>>>(x, ws);
    for (int step = 0; step < 2; step++){
        node_pre<<<(N*64)/256, 256, 0, stream>>>(ws);
        // mess_to: aggregate at col; uniform side PtA (pt rows 0..63), gathered PtB; other end = row
        gather_msgs<<<1024, 256, 0, stream>>>(wsI + CP_OFF, wsI + CIDX_OFF, ei, attr,
                                              ws + PT1_OFF, ws + AT_OFF, ws + BT1_OFF,
                                              ws + WT2_OFF, ws + BT2_OFF,
                                              ws + PGB_OFF, ws + MT_OFF,
                                              ws + H_OFF, ws + FLAG_OFF);
        // mess_from: aggregate at row; uniform side PfA, gathered PfB; other end = col
        gather_msgs<<<1024, 256, 0, stream>>>(wsI + RP_OFF, wsI + RIDX_OFF, ei + E, attr,
                                              ws + PF1_OFF, ws + AF_OFF, ws + BF1_OFF,
                                              ws + WF2_OFF, ws + BF2_OFF,
                                              ws + PGB_OFF + 64, ws + MF_OFF,
                                              ws + H_OFF, ws + FLAG_OFF);
        gate_kernel<<<512, 256, 0, stream>>>(prb, tags, ws);
        decode_loss<<<256, 256, 0, stream>>>(step, ws);
        resid_csr<<<(N + 255)/256, 256, 0, stream>>>(step, ei, aij, y, ws);
    }
    write_out<<<(N + 256)/256, 256, 0, stream>>>(d_out, ws);
}

// Round 4
// 1804.831 us; speedup vs baseline: 7.9236x; 2.7109x over previous
//
#include <hip/hip_runtime.h>

#define DEV __device__ __forceinline__

constexpr int N = 50000;
constexpr int E = 800000;

// ---- float region (4-byte units) ----
constexpr int H0_OFF  = 0;                 // 64N
constexpr int H_OFF   = 64*N;              // 64N
constexpr int MT_OFF  = 128*N;             // 64N (also PGA for 'to' before gather overwrite)
constexpr int MF_OFF  = 192*N;             // 64N (also PGA for 'from')
constexpr int PB_OFF  = 256*N;             // 64N (PtB then PfB)
constexpr int GT_OFF  = 320*N;             // 128N: per node [alpha(64) | rst(64)]
constexpr int TMP_OFF = GT_OFF;            // decode scratch (64N), overlaps dead GT
constexpr int UV_OFF  = 448*N;             // N
constexpr int LOSS_OFF = UV_OFF + N;       // 6 + pad + flag
constexpr int FLAG_OFF = LOSS_OFF + 7;
constexpr int WT2_OFF = LOSS_OFF + 8;      // 4096
constexpr int WF2_OFF = WT2_OFF + 4096;    // 4096
constexpr int AT_OFF  = WF2_OFF + 4096;    // 192
constexpr int AF_OFF  = AT_OFF + 192;      // 192
constexpr int BT1_OFF = AF_OFF + 192;      // 64
constexpr int BT2_OFF = BT1_OFF + 64;      // 64
constexpr int BF1_OFF = BT2_OFF + 64;      // 64
constexpr int BF2_OFF = BF1_OFF + 64;      // 64
constexpr int DW1_OFF = BF2_OFF + 64;      // 4096
constexpr int DW2_OFF = DW1_OFF + 4096;    // 64
constexpr int DB1_OFF = DW2_OFF + 64;      // 64
constexpr int DB2_OFF = DB1_OFF + 64;      // 1 (+3 pad)
constexpr int EW1_OFF = DB2_OFF + 4;       // 64
constexpr int EB1_OFF = EW1_OFF + 64;      // 64
constexpr int EW2_OFF = EB1_OFF + 64;      // 4096
constexpr int EB2_OFF = EW2_OFF + 4096;    // 64
constexpr int CW_OFF  = EB2_OFF + 64;      // 194*64 = 12416 (corr_W full)
constexpr int CB_OFF  = CW_OFF + 12416;    // 64
constexpr int WZR_OFF = CB_OFF + 64;       // 194*128 = 24832 ([k][z(64)|r(64)])
constexpr int GB_OFF  = WZR_OFF + 24832;   // 128 (zkb|rkb)
constexpr int PT1_OFF = GB_OFF + 128;      // 8192
constexpr int PF1_OFF = PT1_OFF + 8192;    // 8192
constexpr int FEND    = PF1_OFF + 8192;
// ---- int region (CSR) ----
constexpr int CP_OFF   = FEND;             // N+1
constexpr int RP_OFF   = CP_OFF + N + 1;   // N+1
constexpr int CF_OFF   = RP_OFF + N + 1;   // N
constexpr int RF_OFF   = CF_OFF + N;       // N
constexpr int CDEG_OFF = RF_OFF + N;       // N
constexpr int RDEG_OFF = CDEG_OFF + N;     // N
constexpr int BS_OFF   = RDEG_OFF + N;     // 512
constexpr int BO_OFF   = BS_OFF + 512;     // 512
constexpr int CIDX_OFF = BO_OFF + 512;     // E
constexpr int RIDX_OFF = CIDX_OFF + E;     // E
constexpr int WS_END   = RIDX_OFF + E;     // ~24.4M * 4B = ~98 MB

constexpr int PREP_TOTAL = 4096+4096+192+192+64+64+64+64+4096+64+64+1+64+64+4096+64+6+12416+64+24832+128+8192+8192;

DEV float b2f(unsigned short u){ return __uint_as_float(((unsigned)u) << 16); }
DEV unsigned short f2b(float f){
    unsigned u = __float_as_uint(f);
    return (unsigned short)((u + 0x7fffu + ((u >> 16) & 1u)) >> 16);
}
DEV float bcastf(float v, int k){
    return __uint_as_float(__builtin_amdgcn_readlane(__float_as_uint(v), k));
}
DEV int bcasti(int v, int k){ return __builtin_amdgcn_readlane(v, k); }
DEV float wave_sum(float v){
    #pragma unroll
    for (int off = 32; off > 0; off >>= 1) v += __shfl_xor(v, off, 64);
    return v;
}
DEV float ldv(const void* p, int i, bool isbf){
    return isbf ? b2f(((const unsigned short*)p)[i]) : ((const float*)p)[i];
}
DEV float sigm(float x){ return 1.f / (1.f + __expf(-x)); }

struct WPtrs {
    const void *ptW1, *ptb1, *ptW2, *ptb2;
    const void *pfW1, *pfb1, *pfW2, *pfb2;
    const void *zkW, *zkb, *rkW, *rkb, *cW, *cb;
    const void *eW1, *eb1, *eW2, *eb2;
    const void *dW1, *db1, *dW2, *db2;
};

// ---- dtype detection ----
__global__ __launch_bounds__(256) void detect_kernel(const void* y, float* __restrict__ ws){
    __shared__ int bad;
    if (threadIdx.x == 0) bad = 0;
    __syncthreads();
    const unsigned short* yy = (const unsigned short*)y;
    int mybad = 0;
    for (int i = threadIdx.x; i < 4096; i += 256){
        float v = b2f(yy[i]);
        if (!(v > -1.0e6f && v < 1.0e6f)) mybad = 1;
    }
    if (mybad) bad = 1;
    __syncthreads();
    if (threadIdx.x == 0) ws[FLAG_OFF] = bad ? 0.0f : 1.0f;
}

// ---- weight prep: (bf16|f32) -> f32 ws copies ----
__global__ __launch_bounds__(256) void prep_kernel(WPtrs P, float* __restrict__ ws){
    int j = blockIdx.x * 256 + threadIdx.x;
    if (j >= PREP_TOTAL) return;
    bool isbf = ws[FLAG_OFF] > 0.5f;
    if (j < 4096){ ws[WT2_OFF+j] = ldv(P.ptW2, j, isbf); return; } j -= 4096;
    if (j < 4096){ ws[WF2_OFF+j] = ldv(P.pfW2, j, isbf); return; } j -= 4096;
    if (j < 192){ ws[AT_OFF+j] = ldv(P.ptW1, 128*64+j, isbf); return; } j -= 192;
    if (j < 192){ ws[AF_OFF+j] = ldv(P.pfW1, 128*64+j, isbf); return; } j -= 192;
    if (j < 64){ ws[BT1_OFF+j] = ldv(P.ptb1, j, isbf); return; } j -= 64;
    if (j < 64){ ws[BT2_OFF+j] = ldv(P.ptb2, j, isbf); return; } j -= 64;
    if (j < 64){ ws[BF1_OFF+j] = ldv(P.pfb1, j, isbf); return; } j -= 64;
    if (j < 64){ ws[BF2_OFF+j] = ldv(P.pfb2, j, isbf); return; } j -= 64;
    if (j < 4096){ ws[DW1_OFF+j] = ldv(P.dW1, j, isbf); return; } j -= 4096;
    if (j < 64){ ws[DW2_OFF+j] = ldv(P.dW2, j, isbf); return; } j -= 64;
    if (j < 64){ ws[DB1_OFF+j] = ldv(P.db1, j, isbf); return; } j -= 64;
    if (j < 1){ ws[DB2_OFF] = ldv(P.db2, 0, isbf); return; } j -= 1;
    if (j < 64){ ws[EW1_OFF+j] = ldv(P.eW1, j, isbf); return; } j -= 64;
    if (j < 64){ ws[EB1_OFF+j] = ldv(P.eb1, j, isbf); return; } j -= 64;
    if (j < 4096){ ws[EW2_OFF+j] = ldv(P.eW2, j, isbf); return; } j -= 4096;
    if (j < 64){ ws[EB2_OFF+j] = ldv(P.eb2, j, isbf); return; } j -= 64;
    if (j < 6){ ws[LOSS_OFF+j] = 0.f; return; } j -= 6;
    if (j < 12416){ ws[CW_OFF+j] = ldv(P.cW, j, isbf); return; } j -= 12416;
    if (j < 64){ ws[CB_OFF+j] = ldv(P.cb, j, isbf); return; } j -= 64;
    if (j < 24832){   // WZR[k][128]: z cols 0..63, r cols 64..127
        int k = j >> 7, c = j & 127;
        ws[WZR_OFF+j] = (c < 64) ? ldv(P.zkW, k*64+c, isbf) : ldv(P.rkW, k*64+(c-64), isbf);
        return;
    } j -= 24832;
    if (j < 128){ ws[GB_OFF+j] = (j < 64) ? ldv(P.zkb, j, isbf) : ldv(P.rkb, j-64, isbf); return; } j -= 128;
    if (j < 8192){ ws[PT1_OFF+j] = ldv(P.ptW1, j, isbf); return; } j -= 8192;
    ws[PF1_OFF+j] = ldv(P.pfW1, j, isbf);
}

// ---- CSR build ----
__global__ __launch_bounds__(256) void zero_deg(int* __restrict__ wsI){
    int i = blockIdx.x * 256 + threadIdx.x;
    if (i < N){ wsI[CDEG_OFF+i] = 0; wsI[RDEG_OFF+i] = 0; }
}
__global__ __launch_bounds__(256) void hist_kernel(const int* __restrict__ ei, int* __restrict__ wsI){
    int e = blockIdx.x * 256 + threadIdx.x;
    if (e >= E) return;
    atomicAdd(&wsI[RDEG_OFF + ei[e]], 1);
    atomicAdd(&wsI[CDEG_OFF + ei[E+e]], 1);
}
__global__ __launch_bounds__(256) void scan1(int* __restrict__ wsI){
    int y = blockIdx.y;
    const int* deg = wsI + (y ? RDEG_OFF : CDEG_OFF);
    int* tmp = wsI + (y ? RP_OFF : CP_OFF);
    int i = blockIdx.x * 256 + threadIdx.x;
    __shared__ int sh[256];
    int v = (i < N) ? deg[i] : 0;
    sh[threadIdx.x] = v;
    __syncthreads();
    #pragma unroll
    for (int off = 1; off < 256; off <<= 1){
        int t = (threadIdx.x >= (unsigned)off) ? sh[threadIdx.x - off] : 0;
        __syncthreads();
        sh[threadIdx.x] += t;
        __syncthreads();
    }
    if (i < N) tmp[i] = sh[threadIdx.x] - v;
    if (threadIdx.x == 255) wsI[BS_OFF + y*256 + blockIdx.x] = sh[255];
}
__global__ __launch_bounds__(256) void scan2(int* __restrict__ wsI){
    int y = blockIdx.y, t = threadIdx.x;
    __shared__ int sh[256];
    int v = (t < 196) ? wsI[BS_OFF + y*256 + t] : 0;
    sh[t] = v;
    __syncthreads();
    #pragma unroll
    for (int off = 1; off < 256; off <<= 1){
        int u = (t >= (unsigned)off) ? sh[t - off] : 0;
        __syncthreads();
        sh[t] += u;
        __syncthreads();
    }
    wsI[BO_OFF + y*256 + t] = sh[t] - v;
}
__global__ __launch_bounds__(256) void scan3(int* __restrict__ wsI){
    int y = blockIdx.y;
    int* ptr  = wsI + (y ? RP_OFF : CP_OFF);
    int* fill = wsI + (y ? RF_OFF : CF_OFF);
    int i = blockIdx.x * 256 + threadIdx.x;
    if (i < N){
        int p = ptr[i] + wsI[BO_OFF + y*256 + blockIdx.x];
        ptr[i] = p; fill[i] = p;
    }
    if (blockIdx.x == 0 && threadIdx.x == 0) ptr[N] = E;
}
__global__ __launch_bounds__(256) void scatter_kernel(const int* __restrict__ ei, int* __restrict__ wsI){
    int e = blockIdx.x * 256 + threadIdx.x;
    if (e >= E) return;
    int r = ei[e], c = ei[E+e];
    int q = atomicAdd(&wsI[RF_OFF + r], 1);
    wsI[RIDX_OFF + q] = e;
    int p = atomicAdd(&wsI[CF_OFF + c], 1);
    wsI[CIDX_OFF + p] = e;
}

// ---- encoder: H0 = relu(x*eW1 + eb1) @ eW2 + eb2 ; H = H0 ----
__global__ __launch_bounds__(256) void encode_init(const void* __restrict__ x,
                                                   float* __restrict__ ws){
    int idx = blockIdx.x * 256 + threadIdx.x;
    if (idx >= N*64) return;
    bool isbf = ws[FLAG_OFF] > 0.5f;
    int node = idx >> 6, f = idx & 63;
    float xv = ldv(x, node, isbf);
    float acc = ws[EB2_OFF+f];
    #pragma unroll
    for (int k = 0; k < 64; k++){
        float t = fmaxf(fmaf(xv, ws[EW1_OFF+k], ws[EB1_OFF+k]), 0.f);
        acc = fmaf(t, ws[EW2_OFF + k*64 + f], acc);
    }
    ws[H0_OFF+idx] = acc;
    ws[H_OFF+idx]  = acc;
}

// ---- per-direction first-layer precompute: A-part -> outA (aliased w/ gather out), B-part -> PB ----
__global__ __launch_bounds__(256) void node_pre(const float* __restrict__ W1,
                                                float* __restrict__ outA,
                                                float* __restrict__ ws){
    int idx = blockIdx.x * 256 + threadIdx.x;
    if (idx >= N*64) return;
    int node = idx >> 6, f = idx & 63;
    const float* Hp = ws + H_OFF + (size_t)node*64;
    float aA = 0.f, aB = 0.f;
    #pragma unroll
    for (int k = 0; k < 64; k++){
        float hv = Hp[k];
        aA = fmaf(hv, W1[k*64+f],      aA);
        aB = fmaf(hv, W1[(64+k)*64+f], aB);
    }
    outA[idx] = aA;
    ws[PB_OFF+idx] = aB;
}

// ---- CSR message gather: wave per node, lane = feature; writes over pga in place ----
__global__ __launch_bounds__(256) void gather_msgs(const int* __restrict__ csrPtr,
                                                   const int* __restrict__ csrIdx,
                                                   const int* __restrict__ other,
                                                   const void* __restrict__ attr,
                                                   const float* __restrict__ A3,
                                                   const float* __restrict__ b1,
                                                   const float* __restrict__ W2,
                                                   const float* __restrict__ b2,
                                                   float* __restrict__ pga,   // in: A-part, out: message
                                                   const float* __restrict__ pgb,
                                                   const float* __restrict__ flagp){
    bool isbf = *flagp > 0.5f;
    int lane = threadIdx.x & 63;
    int wv = threadIdx.x >> 6;
    float W2c[64];
    #pragma unroll
    for (int k = 0; k < 64; k++) W2c[k] = W2[k*64 + lane];
    float A0 = A3[lane], A1 = A3[64+lane], A2 = A3[128+lane];
    float B1 = b1[lane], B2 = b2[lane];
    int gw = blockIdx.x * 4 + wv;
    int nw = gridDim.x * 4;
    for (int node = gw; node < N; node += nw){
        float pa = pga[(size_t)node*64 + lane];
        float hs = 0.f;
        int cnt = 0;
        int beg = csrPtr[node], end = csrPtr[node+1];
        for (int base = beg; base < end; base += 64){
            int mcnt = end - base; if (mcnt > 64) mcnt = 64;
            int eL = 0, oL = 0;
            float a0L = 0.f, a1L = 0.f, a2L = 0.f;
            if (lane < mcnt){
                eL = csrIdx[base + lane];
                oL = other[eL];
                a0L = ldv(attr, 3*eL,   isbf);
                a1L = ldv(attr, 3*eL+1, isbf);
                a2L = ldv(attr, 3*eL+2, isbf);
            }
            for (int t = 0; t < mcnt; t++){
                int o = bcasti(oL, t);
                if (o == node) continue;
                float a0 = bcastf(a0L, t), a1 = bcastf(a1L, t), a2 = bcastf(a2L, t);
                float pb = pgb[(size_t)o*64 + lane];
                float hv = pa + pb + a0*A0 + a1*A1 + a2*A2 + B1;
                hs += fmaxf(hv, 0.f);
                cnt++;
            }
        }
        float m = (float)cnt * B2;
        #pragma unroll
        for (int k = 0; k < 64; k++) m = fmaf(bcastf(hs, k), W2c[k], m);
        pga[(size_t)node*64 + lane] = m;
    }
}

// ---- gate phase 1: z / r (chunk = blockIdx.y), thread per node ----
__global__ __launch_bounds__(256) void gate_zr(const void* __restrict__ prb,
                                               float* __restrict__ ws){
    int node = blockIdx.x * 256 + threadIdx.x;
    if (node >= N) return;
    bool isbf = ws[FLAG_OFF] > 0.5f;
    int ch = blockIdx.y;            // 0 = z, 1 = r
    const float* W = ws + WZR_OFF + ch*64;    // [k][128] with column offset
    float p0 = ldv(prb, 2*node, isbf), p1 = ldv(prb, 2*node+1, isbf);
    float acc[64];
    #pragma unroll
    for (int j = 0; j < 64; j++)
        acc[j] = ws[GB_OFF + ch*64 + j] + p0*W[192*128+j] + p1*W[193*128+j];
    const float* X0 = ws + H_OFF  + (size_t)node*64;
    const float* X1 = ws + MT_OFF + (size_t)node*64;
    const float* X2 = ws + MF_OFF + (size_t)node*64;
    for (int k = 0; k < 64; k++){
        float a = X0[k]; const float* wr = W + (size_t)k*128;
        #pragma unroll
        for (int j = 0; j < 64; j++) acc[j] = fmaf(a, wr[j], acc[j]);
    }
    for (int k = 0; k < 64; k++){
        float a = X1[k]; const float* wr = W + (size_t)(64+k)*128;
        #pragma unroll
        for (int j = 0; j < 64; j++) acc[j] = fmaf(a, wr[j], acc[j]);
    }
    for (int k = 0; k < 64; k++){
        float a = X2[k]; const float* wr = W + (size_t)(128+k)*128;
        #pragma unroll
        for (int j = 0; j < 64; j++) acc[j] = fmaf(a, wr[j], acc[j]);
    }
    float* g = ws + GT_OFF + (size_t)node*128 + ch*64;
    #pragma unroll
    for (int j = 0; j < 64; j++) g[j] = sigm(acc[j]);
}

// ---- gate phase 2: corr + state update, thread per node ----
__global__ __launch_bounds__(256) void gate_corr(const void* __restrict__ prb,
                                                 const int* __restrict__ tags,
                                                 float* __restrict__ ws){
    int node = blockIdx.x * 256 + threadIdx.x;
    if (node >= N) return;
    bool isbf = ws[FLAG_OFF] > 0.5f;
    const float* CW = ws + CW_OFF;
    float p0 = ldv(prb, 2*node, isbf), p1 = ldv(prb, 2*node+1, isbf);
    float acc[64];
    #pragma unroll
    for (int j = 0; j < 64; j++)
        acc[j] = ws[CB_OFF+j] + p0*CW[192*64+j] + p1*CW[193*64+j];
    const float* Hp = ws + H_OFF  + (size_t)node*64;
    const float* Mt = ws + MT_OFF + (size_t)node*64;
    const float* Mf = ws + MF_OFF + (size_t)node*64;
    const float* Gp = ws + GT_OFF + (size_t)node*128;
    for (int k = 0; k < 64; k++){
        float a = Gp[64+k] * Hp[k];          // reset * H
        const float* wr = CW + (size_t)k*64;
        #pragma unroll
        for (int j = 0; j < 64; j++) acc[j] = fmaf(a, wr[j], acc[j]);
    }
    for (int k = 0; k < 64; k++){
        float a = Mt[k]; const float* wr = CW + (size_t)(64+k)*64;
        #pragma unroll
        for (int j = 0; j < 64; j++) acc[j] = fmaf(a, wr[j], acc[j]);
    }
    for (int k = 0; k < 64; k++){
        float a = Mf[k]; const float* wr = CW + (size_t)(128+k)*64;
        #pragma unroll
        for (int j = 0; j < 64; j++) acc[j] = fmaf(a, wr[j], acc[j]);
    }
    int tg = tags[node];
    float* Hw = ws + H_OFF + (size_t)node*64;
    const float* H0p = ws + H0_OFF + (size_t)node*64;
    #pragma unroll
    for (int j = 0; j < 64; j++){
        float hn = fmaf(Gp[j], tanhf(acc[j]), Hw[j]);
        if (tg == 1) hn = H0p[j];
        Hw[j] = hn;
    }
}

// ---- decoder + enc/auto losses, thread per node ----
__global__ __launch_bounds__(256) void decode_loss(int step, float* __restrict__ ws){
    int node = blockIdx.x * 256 + threadIdx.x;
    float encA = 0.f, autoA = 0.f;
    if (node < N){
        const float* Hp = ws + H_OFF + (size_t)node*64;
        float acc[64];
        #pragma unroll
        for (int j = 0; j < 64; j++) acc[j] = ws[DB1_OFF+j];
        for (int k = 0; k < 64; k++){
            float a = Hp[k]; const float* wr = ws + DW1_OFF + (size_t)k*64;
            #pragma unroll
            for (int j = 0; j < 64; j++) acc[j] = fmaf(a, wr[j], acc[j]);
        }
        float u = ws[DB2_OFF];
        #pragma unroll
        for (int j = 0; j < 64; j++) u = fmaf(fmaxf(acc[j], 0.f), ws[DW2_OFF+j], u);
        ws[UV_OFF+node] = u;
        // encode(u)
        #pragma unroll
        for (int j = 0; j < 64; j++) acc[j] = ws[EB2_OFF+j];
        for (int k = 0; k < 64; k++){
            float t = fmaxf(fmaf(u, ws[EW1_OFF+k], ws[EB1_OFF+k]), 0.f);
            const float* wr = ws + EW2_OFF + (size_t)k*64;
            #pragma unroll
            for (int j = 0; j < 64; j++) acc[j] = fmaf(t, wr[j], acc[j]);
        }
        float* Tp = ws + TMP_OFF + (size_t)node*64;
        #pragma unroll
        for (int j = 0; j < 64; j++){
            float d = acc[j] - Hp[j];
            encA += d*d;
            Tp[j] = acc[j];
        }
        // decode(encode(u))
        #pragma unroll
        for (int j = 0; j < 64; j++) acc[j] = ws[DB1_OFF+j];
        for (int k = 0; k < 64; k++){
            float a = Tp[k]; const float* wr = ws + DW1_OFF + (size_t)k*64;
            #pragma unroll
            for (int j = 0; j < 64; j++) acc[j] = fmaf(a, wr[j], acc[j]);
        }
        float u2 = ws[DB2_OFF];
        #pragma unroll
        for (int j = 0; j < 64; j++) u2 = fmaf(fmaxf(acc[j], 0.f), ws[DW2_OFF+j], u2);
        float ad = u2 - u;
        autoA = ad*ad;
    }
    encA = wave_sum(encA);
    autoA = wave_sum(autoA);
    if ((threadIdx.x & 63) == 0){
        atomicAdd(&ws[LOSS_OFF + step*3 + 1], encA);
        atomicAdd(&ws[LOSS_OFF + step*3 + 2], autoA);
    }
}

// ---- residual via row-CSR gather (self-loops INCLUDED) ----
__global__ __launch_bounds__(256) void resid_csr(int step, const int* __restrict__ ei,
                                                 const void* __restrict__ aij,
                                                 const void* __restrict__ y,
                                                 float* __restrict__ ws){
    const int* wsI = (const int*)ws;
    int i = blockIdx.x * 256 + threadIdx.x;
    bool isbf = ws[FLAG_OFF] > 0.5f;
    float s = 0.f;
    if (i < N){
        float acc = 0.f;
        int beg = wsI[RP_OFF+i], end = wsI[RP_OFF+i+1];
        for (int j = beg; j < end; j++){
            int e = wsI[RIDX_OFF+j];
            int c = ei[E+e];
            acc = fmaf(ldv(aij, e, isbf), ws[UV_OFF+c], acc);
        }
        float d = acc - ldv(y, i, isbf);
        s = d*d;
    }
    s = wave_sum(s);
    if ((threadIdx.x & 63) == 0) atomicAdd(&ws[LOSS_OFF + step*3], s);
}

// ---- output writer ----
__global__ __launch_bounds__(256) void write_out(void* __restrict__ outp,
                                                 const float* __restrict__ ws){
    int i = blockIdx.x * 256 + threadIdx.x;
    if (i > N) return;
    bool isbf = ws[FLAG_OFF] > 0.5f;
    float v;
    if (i < N){
        v = ws[UV_OFF+i];
    } else {
        const float* L = ws + LOSS_OFF;
        float inv = 1.f / (float)N, invl = 1.f / ((float)N * 64.f);
        v = 0.9f*L[0]*inv + L[1]*invl + L[2]*inv
          +      L[3]*inv + L[4]*invl + L[5]*inv;
    }
    if (isbf) ((unsigned short*)outp)[i] = f2b(v);
    else      ((float*)outp)[i] = v;
}

extern "C" void kernel_launch(void* const* d_in, const int* in_sizes, int n_in,
                              void* d_out, int out_size, void* d_ws, size_t ws_size,
                              hipStream_t stream){
    const void* x    = d_in[0];
    const void* y    = d_in[2];
    const int* tags  = (const int*)d_in[3];
    const int* ei    = (const int*)d_in[4];
    const void* attr = d_in[5];
    const void* aij  = d_in[6];
    const void* prb  = d_in[7];
    WPtrs P;
    P.ptW1 = d_in[8];  P.ptb1 = d_in[9];  P.ptW2 = d_in[10]; P.ptb2 = d_in[11];
    P.pfW1 = d_in[12]; P.pfb1 = d_in[13]; P.pfW2 = d_in[14]; P.pfb2 = d_in[15];
    P.zkW  = d_in[16]; P.zkb  = d_in[17]; P.rkW  = d_in[18]; P.rkb  = d_in[19];
    P.cW   = d_in[20]; P.cb   = d_in[21];
    P.eW1  = d_in[22]; P.eb1  = d_in[23]; P.eW2  = d_in[24]; P.eb2  = d_in[25];
    P.dW1  = d_in[26]; P.db1  = d_in[27]; P.dW2  = d_in[28]; P.db2  = d_in[29];
    float* ws = (float*)d_ws;
    int* wsI = (int*)d_ws;

    detect_kernel<<<1, 256, 0, stream>>>(y, ws);
    prep_kernel<<<(PREP_TOTAL + 255)/256, 256, 0, stream>>>(P, ws);
    // CSR build
    zero_deg<<<196, 256, 0, stream>>>(wsI);
    hist_kernel<<<E/256, 256, 0, stream>>>(ei, wsI);
    scan1<<<dim3(196, 2), 256, 0, stream>>>(wsI);
    scan2<<<dim3(1, 2), 256, 0, stream>>>(wsI);
    scan3<<<dim3(196, 2), 256, 0, stream>>>(wsI);
    scatter_kernel<<<E/256, 256, 0, stream>>>(ei, wsI);
    encode_init<<<(N*64)/256, 256, 0, stream>>>(x, ws);
    for (int step = 0; step < 2; step++){
        // mess_to: aggregate at col; uniform side = ptW1 rows 0..63 @ H[col], gathered = rows 64..127 @ H[row]
        node_pre<<<(N*64)/256, 256, 0, stream>>>(ws + PT1_OFF, ws + MT_OFF, ws);
        gather_msgs<<<1024, 256, 0, stream>>>(wsI + CP_OFF, wsI + CIDX_OFF, ei, attr,
                                              ws + AT_OFF, ws + BT1_OFF, ws + WT2_OFF, ws + BT2_OFF,
                                              ws + MT_OFF, ws + PB_OFF, ws + FLAG_OFF);
        // mess_from: aggregate at row; uniform side = pfW1 rows 0..63 @ H[row], gathered = rows 64..127 @ H[col]
        node_pre<<<(N*64)/256, 256, 0, stream>>>(ws + PF1_OFF, ws + MF_OFF, ws);
        gather_msgs<<<1024, 256, 0, stream>>>(wsI + RP_OFF, wsI + RIDX_OFF, ei + E, attr,
                                              ws + AF_OFF, ws + BF1_OFF, ws + WF2_OFF, ws + BF2_OFF,
                                              ws + MF_OFF, ws + PB_OFF, ws + FLAG_OFF);
        gate_zr<<<dim3(196, 2), 256, 0, stream>>>(prb, ws);
        gate_corr<<<196, 256, 0, stream>>>(prb, tags, ws);
        decode_loss<<<196, 256, 0, stream>>>(step, ws);
        resid_csr<<<196, 256, 0, stream>>>(step, ei, aij, y, ws);
    }
    write_out<<<197, 256, 0, stream>>>(d_out, ws);
}

// Round 5
// 1652.770 us; speedup vs baseline: 8.6526x; 1.0920x over previous
//
#include <hip/hip_runtime.h>

#define DEV __device__ __forceinline__

constexpr int N = 50000;
constexpr int E = 800000;

// ---- float region (4-byte units), feature-major state [feat][node] ----
constexpr int HF_OFF  = 0;                  // 64N  H (feature-major)
constexpr int H0F_OFF = 64*N;               // 64N  H0
constexpr int MTF_OFF = 128*N;              // 64N  mess_to (feature-major)
constexpr int MFF_OFF = 192*N;              // 64N  mess_from
// shared region (128N), phase-dependent:
//   messages: PA (node-major, also gather msg out) | PB (node-major)
//   gate:     ALPHA [64][N]                        | RH = sigm(r)*H [64][N]
//   decode:   T1 / T2 [64][N]                      | Evec [64][N]
constexpr int SH_OFF  = 256*N;
constexpr int PA_OFF  = SH_OFF;             // 64N
constexpr int PB_OFF  = SH_OFF + 64*N;      // 64N
constexpr int AL_OFF  = SH_OFF;             // alpha
constexpr int RH_OFF  = SH_OFF + 64*N;      // sigm(r)*H
constexpr int T1_OFF  = SH_OFF;             // relu(dec layer1)
constexpr int EV_OFF  = SH_OFF + 64*N;      // encode(u)
constexpr int UV_OFF  = 384*N;              // N
constexpr int LOSS_OFF = UV_OFF + N;        // 6 loss + pad + flag
constexpr int FLAG_OFF = LOSS_OFF + 7;
// weights (f32 copies)
constexpr int WB      = LOSS_OFF + 8;
constexpr int WZR_OFF = WB;                 // 194*128: [k][ z(64) | r(64) ]
constexpr int GB_OFF  = WZR_OFF + 24832;    // 128: zb|rb
constexpr int CW_OFF  = GB_OFF + 128;       // 194*64
constexpr int CB_OFF  = CW_OFF + 12416;     // 64
constexpr int PT1_OFF = CB_OFF + 64;        // 8192 (pt_W1 rows 0..127)
constexpr int AT_OFF  = PT1_OFF + 8192;     // 192 (pt_W1 rows 128..130)
constexpr int BT1_OFF = AT_OFF + 192;       // 64
constexpr int WT2_OFF = BT1_OFF + 64;       // 4096
constexpr int BT2_OFF = WT2_OFF + 4096;     // 64
constexpr int PF1_OFF = BT2_OFF + 64;       // 8192
constexpr int AF_OFF  = PF1_OFF + 8192;     // 192
constexpr int BF1_OFF = AF_OFF + 192;       // 64
constexpr int WF2_OFF = BF1_OFF + 64;       // 4096
constexpr int BF2_OFF = WF2_OFF + 4096;     // 64
constexpr int DW1_OFF = BF2_OFF + 64;       // 4096
constexpr int DW2_OFF = DW1_OFF + 4096;     // 64
constexpr int DB1_OFF = DW2_OFF + 64;       // 64
constexpr int DB2_OFF = DB1_OFF + 64;       // 1 (+3 pad)
constexpr int EW1_OFF = DB2_OFF + 4;        // 64
constexpr int EB1_OFF = EW1_OFF + 64;       // 64
constexpr int EW2_OFF = EB1_OFF + 64;       // 4096
constexpr int EB2_OFF = EW2_OFF + 4096;     // 64
constexpr int PRB0_OFF = EB2_OFF + 64;      // N
constexpr int PRB1_OFF = PRB0_OFF + N;      // N
constexpr int FEND    = PRB1_OFF + N;
// int region (CSR)
constexpr int CP_OFF   = FEND;              // N+1
constexpr int RP_OFF   = CP_OFF + N + 1;    // N+1
constexpr int CF_OFF   = RP_OFF + N + 1;    // N
constexpr int RF_OFF   = CF_OFF + N;        // N
constexpr int CDEG_OFF = RF_OFF + N;        // N
constexpr int RDEG_OFF = CDEG_OFF + N;      // N
constexpr int BS_OFF   = RDEG_OFF + N;      // 512
constexpr int BO_OFF   = BS_OFF + 512;      // 512
constexpr int CIDX_OFF = BO_OFF + 512;      // E
constexpr int RIDX_OFF = CIDX_OFF + E;      // E  (total ~85 MB)

constexpr int PREP_TOTAL = 24832+128+12416+64+8192+192+64+4096+64+8192+192+64+4096+64+4096+64+64+1+64+64+4096+64+6;

DEV float b2f(unsigned short u){ return __uint_as_float(((unsigned)u) << 16); }
DEV unsigned short f2b(float f){
    unsigned u = __float_as_uint(f);
    return (unsigned short)((u + 0x7fffu + ((u >> 16) & 1u)) >> 16);
}
DEV float bcastf(float v, int k){
    return __uint_as_float(__builtin_amdgcn_readlane(__float_as_uint(v), k));
}
DEV int bcasti(int v, int k){ return __builtin_amdgcn_readlane(v, k); }
DEV float wave_sum(float v){
    #pragma unroll
    for (int off = 32; off > 0; off >>= 1) v += __shfl_xor(v, off, 64);
    return v;
}
DEV float ldv(const void* p, int i, bool isbf){
    return isbf ? b2f(((const unsigned short*)p)[i]) : ((const float*)p)[i];
}
DEV float sigm(float x){ return 1.f / (1.f + __expf(-x)); }

struct WPtrs {
    const void *ptW1, *ptb1, *ptW2, *ptb2;
    const void *pfW1, *pfb1, *pfW2, *pfb2;
    const void *zkW, *zkb, *rkW, *rkb, *cW, *cb;
    const void *eW1, *eb1, *eW2, *eb2;
    const void *dW1, *db1, *dW2, *db2;
};

// ---- dtype detection ----
__global__ __launch_bounds__(256) void detect_kernel(const void* y, float* __restrict__ ws){
    __shared__ int bad;
    if (threadIdx.x == 0) bad = 0;
    __syncthreads();
    const unsigned short* yy = (const unsigned short*)y;
    int mybad = 0;
    for (int i = threadIdx.x; i < 4096; i += 256){
        float v = b2f(yy[i]);
        if (!(v > -1.0e6f && v < 1.0e6f)) mybad = 1;
    }
    if (mybad) bad = 1;
    __syncthreads();
    if (threadIdx.x == 0) ws[FLAG_OFF] = bad ? 0.0f : 1.0f;
}

// ---- weight prep ----
__global__ __launch_bounds__(256) void prep_kernel(WPtrs P, float* __restrict__ ws){
    int j = blockIdx.x * 256 + threadIdx.x;
    if (j >= PREP_TOTAL) return;
    bool isbf = ws[FLAG_OFF] > 0.5f;
    if (j < 24832){   // WZR[k][128]
        int k = j >> 7, c = j & 127;
        ws[WZR_OFF+j] = (c < 64) ? ldv(P.zkW, k*64+c, isbf) : ldv(P.rkW, k*64+(c-64), isbf);
        return;
    } j -= 24832;
    if (j < 128){ ws[GB_OFF+j] = (j < 64) ? ldv(P.zkb, j, isbf) : ldv(P.rkb, j-64, isbf); return; } j -= 128;
    if (j < 12416){ ws[CW_OFF+j] = ldv(P.cW, j, isbf); return; } j -= 12416;
    if (j < 64){ ws[CB_OFF+j] = ldv(P.cb, j, isbf); return; } j -= 64;
    if (j < 8192){ ws[PT1_OFF+j] = ldv(P.ptW1, j, isbf); return; } j -= 8192;
    if (j < 192){ ws[AT_OFF+j] = ldv(P.ptW1, 128*64+j, isbf); return; } j -= 192;
    if (j < 64){ ws[BT1_OFF+j] = ldv(P.ptb1, j, isbf); return; } j -= 64;
    if (j < 4096){ ws[WT2_OFF+j] = ldv(P.ptW2, j, isbf); return; } j -= 4096;
    if (j < 64){ ws[BT2_OFF+j] = ldv(P.ptb2, j, isbf); return; } j -= 64;
    if (j < 8192){ ws[PF1_OFF+j] = ldv(P.pfW1, j, isbf); return; } j -= 8192;
    if (j < 192){ ws[AF_OFF+j] = ldv(P.pfW1, 128*64+j, isbf); return; } j -= 192;
    if (j < 64){ ws[BF1_OFF+j] = ldv(P.pfb1, j, isbf); return; } j -= 64;
    if (j < 4096){ ws[WF2_OFF+j] = ldv(P.pfW2, j, isbf); return; } j -= 4096;
    if (j < 64){ ws[BF2_OFF+j] = ldv(P.pfb2, j, isbf); return; } j -= 64;
    if (j < 4096){ ws[DW1_OFF+j] = ldv(P.dW1, j, isbf); return; } j -= 4096;
    if (j < 64){ ws[DW2_OFF+j] = ldv(P.dW2, j, isbf); return; } j -= 64;
    if (j < 64){ ws[DB1_OFF+j] = ldv(P.db1, j, isbf); return; } j -= 64;
    if (j < 1){ ws[DB2_OFF] = ldv(P.db2, 0, isbf); return; } j -= 1;
    if (j < 64){ ws[EW1_OFF+j] = ldv(P.eW1, j, isbf); return; } j -= 64;
    if (j < 64){ ws[EB1_OFF+j] = ldv(P.eb1, j, isbf); return; } j -= 64;
    if (j < 4096){ ws[EW2_OFF+j] = ldv(P.eW2, j, isbf); return; } j -= 4096;
    if (j < 64){ ws[EB2_OFF+j] = ldv(P.eb2, j, isbf); return; } j -= 64;
    ws[LOSS_OFF+j] = 0.f;
}

__global__ __launch_bounds__(256) void prb_split(const void* __restrict__ prb, float* __restrict__ ws){
    int i = blockIdx.x * 256 + threadIdx.x;
    if (i >= N) return;
    bool isbf = ws[FLAG_OFF] > 0.5f;
    ws[PRB0_OFF+i] = ldv(prb, 2*i,   isbf);
    ws[PRB1_OFF+i] = ldv(prb, 2*i+1, isbf);
}

// ---- CSR build ----
__global__ __launch_bounds__(256) void zero_deg(int* __restrict__ wsI){
    int i = blockIdx.x * 256 + threadIdx.x;
    if (i < N){ wsI[CDEG_OFF+i] = 0; wsI[RDEG_OFF+i] = 0; }
}
__global__ __launch_bounds__(256) void hist_kernel(const int* __restrict__ ei, int* __restrict__ wsI){
    int e = blockIdx.x * 256 + threadIdx.x;
    if (e >= E) return;
    atomicAdd(&wsI[RDEG_OFF + ei[e]], 1);
    atomicAdd(&wsI[CDEG_OFF + ei[E+e]], 1);
}
__global__ __launch_bounds__(256) void scan1(int* __restrict__ wsI){
    int y = blockIdx.y;
    const int* deg = wsI + (y ? RDEG_OFF : CDEG_OFF);
    int* tmp = wsI + (y ? RP_OFF : CP_OFF);
    int i = blockIdx.x * 256 + threadIdx.x;
    __shared__ int sh[256];
    int v = (i < N) ? deg[i] : 0;
    sh[threadIdx.x] = v;
    __syncthreads();
    #pragma unroll
    for (int off = 1; off < 256; off <<= 1){
        int t = (threadIdx.x >= (unsigned)off) ? sh[threadIdx.x - off] : 0;
        __syncthreads();
        sh[threadIdx.x] += t;
        __syncthreads();
    }
    if (i < N) tmp[i] = sh[threadIdx.x] - v;
    if (threadIdx.x == 255) wsI[BS_OFF + y*256 + blockIdx.x] = sh[255];
}
__global__ __launch_bounds__(256) void scan2(int* __restrict__ wsI){
    int y = blockIdx.y, t = threadIdx.x;
    __shared__ int sh[256];
    int v = (t < 196) ? wsI[BS_OFF + y*256 + t] : 0;
    sh[t] = v;
    __syncthreads();
    #pragma unroll
    for (int off = 1; off < 256; off <<= 1){
        int u = (t >= (unsigned)off) ? sh[t - off] : 0;
        __syncthreads();
        sh[t] += u;
        __syncthreads();
    }
    wsI[BO_OFF + y*256 + t] = sh[t] - v;
}
__global__ __launch_bounds__(256) void scan3(int* __restrict__ wsI){
    int y = blockIdx.y;
    int* ptr  = wsI + (y ? RP_OFF : CP_OFF);
    int* fill = wsI + (y ? RF_OFF : CF_OFF);
    int i = blockIdx.x * 256 + threadIdx.x;
    if (i < N){
        int p = ptr[i] + wsI[BO_OFF + y*256 + blockIdx.x];
        ptr[i] = p; fill[i] = p;
    }
    if (blockIdx.x == 0 && threadIdx.x == 0) ptr[N] = E;
}
__global__ __launch_bounds__(256) void scatter_kernel(const int* __restrict__ ei, int* __restrict__ wsI){
    int e = blockIdx.x * 256 + threadIdx.x;
    if (e >= E) return;
    int r = ei[e], c = ei[E+e];
    int q = atomicAdd(&wsI[RF_OFF + r], 1);
    wsI[RIDX_OFF + q] = e;
    int p = atomicAdd(&wsI[CF_OFF + c], 1);
    wsI[CIDX_OFF + p] = e;
}

// ---- encoder: H0/H feature-major, thread per node, j-tile 32 ----
__global__ __launch_bounds__(256) void encode_init(const void* __restrict__ x,
                                                   float* __restrict__ ws){
    int node = blockIdx.x * 256 + threadIdx.x;
    if (node >= N) return;
    bool isbf = ws[FLAG_OFF] > 0.5f;
    int j0 = blockIdx.y * 32;
    float xv = ldv(x, node, isbf);
    float acc[32];
    #pragma unroll
    for (int j = 0; j < 32; j++) acc[j] = ws[EB2_OFF + j0 + j];
    for (int k = 0; k < 64; k++){
        float t = fmaxf(fmaf(xv, ws[EW1_OFF+k], ws[EB1_OFF+k]), 0.f);
        const float* wr = ws + EW2_OFF + (size_t)k*64 + j0;
        #pragma unroll
        for (int j = 0; j < 32; j++) acc[j] = fmaf(t, wr[j], acc[j]);
    }
    #pragma unroll
    for (int j = 0; j < 32; j++){
        ws[H0F_OFF + (size_t)(j0+j)*N + node] = acc[j];
        ws[HF_OFF  + (size_t)(j0+j)*N + node] = acc[j];
    }
}

// ---- per-direction first-layer precompute (PA,PB node-major) ----
__global__ __launch_bounds__(256) void node_pre(const float* __restrict__ W1,
                                                float* __restrict__ ws){
    int idx = blockIdx.x * 256 + threadIdx.x;
    if (idx >= N*64) return;
    int node = idx >> 6, f = idx & 63;
    float aA = 0.f, aB = 0.f;
    for (int k = 0; k < 64; k++){
        float hv = ws[HF_OFF + (size_t)k*N + node];   // wave-broadcast
        aA = fmaf(hv, W1[k*64+f],      aA);
        aB = fmaf(hv, W1[(64+k)*64+f], aB);
    }
    ws[PA_OFF+idx] = aA;
    ws[PB_OFF+idx] = aB;
}

// ---- CSR message gather: wave per node, lane = feature; writes msg over PA ----
__global__ __launch_bounds__(256) void gather_msgs(const int* __restrict__ csrPtr,
                                                   const int* __restrict__ csrIdx,
                                                   const int* __restrict__ other,
                                                   const void* __restrict__ attr,
                                                   const float* __restrict__ A3,
                                                   const float* __restrict__ b1,
                                                   const float* __restrict__ W2,
                                                   const float* __restrict__ b2,
                                                   float* __restrict__ ws){
    float* pga = ws + PA_OFF;
    const float* pgb = ws + PB_OFF;
    bool isbf = ws[FLAG_OFF] > 0.5f;
    int lane = threadIdx.x & 63;
    int wv = threadIdx.x >> 6;
    float W2c[64];
    #pragma unroll
    for (int k = 0; k < 64; k++) W2c[k] = W2[k*64 + lane];
    float A0 = A3[lane], A1 = A3[64+lane], A2 = A3[128+lane];
    float B1 = b1[lane], B2 = b2[lane];
    int gw = blockIdx.x * 4 + wv;
    int nw = gridDim.x * 4;
    for (int node = gw; node < N; node += nw){
        float pa = pga[(size_t)node*64 + lane];
        float hs = 0.f;
        int cnt = 0;
        int beg = csrPtr[node], end = csrPtr[node+1];
        for (int base = beg; base < end; base += 64){
            int mcnt = end - base; if (mcnt > 64) mcnt = 64;
            int eL = 0, oL = 0;
            float a0L = 0.f, a1L = 0.f, a2L = 0.f;
            if (lane < mcnt){
                eL = csrIdx[base + lane];
                oL = other[eL];
                a0L = ldv(attr, 3*eL,   isbf);
                a1L = ldv(attr, 3*eL+1, isbf);
                a2L = ldv(attr, 3*eL+2, isbf);
            }
            for (int t = 0; t < mcnt; t++){
                int o = bcasti(oL, t);
                if (o == node) continue;
                float a0 = bcastf(a0L, t), a1 = bcastf(a1L, t), a2 = bcastf(a2L, t);
                float pb = pgb[(size_t)o*64 + lane];
                float hv = pa + pb + a0*A0 + a1*A1 + a2*A2 + B1;
                hs += fmaxf(hv, 0.f);
                cnt++;
            }
        }
        float m = (float)cnt * B2;
        #pragma unroll
        for (int k = 0; k < 64; k++) m = fmaf(bcastf(hs, k), W2c[k], m);
        pga[(size_t)node*64 + lane] = m;
    }
}

// ---- transpose PA [node][64] -> dst [64][N] ----
__global__ __launch_bounds__(256) void transpose_msg(const float* __restrict__ src,
                                                     float* __restrict__ dst){
    __shared__ float t[64][65];
    int n0 = blockIdx.x * 64;
    #pragma unroll
    for (int i = 0; i < 16; i++){
        int idx = i*256 + threadIdx.x;
        int nl = idx >> 6, f = idx & 63;
        int node = n0 + nl;
        t[nl][f] = (node < N) ? src[(size_t)node*64 + f] : 0.f;
    }
    __syncthreads();
    #pragma unroll
    for (int i = 0; i < 16; i++){
        int idx = i*256 + threadIdx.x;
        int fw = idx >> 6, nl = idx & 63;
        int node = n0 + nl;
        if (node < N) dst[(size_t)fw*N + node] = t[nl][fw];
    }
}

// ---- gate z/r: thread per node, j-tile 32; RH stored as sigm(r)*H ----
__global__ __launch_bounds__(256) void gate_zr(float* __restrict__ ws){
    int node = blockIdx.x * 256 + threadIdx.x;
    if (node >= N) return;
    int ch = blockIdx.y >> 1, tl = blockIdx.y & 1;
    const float* W = ws + WZR_OFF + ch*64 + tl*32;   // + k*128 + j
    float p0 = ws[PRB0_OFF+node], p1 = ws[PRB1_OFF+node];
    float acc[32];
    #pragma unroll
    for (int j = 0; j < 32; j++)
        acc[j] = ws[GB_OFF + ch*64 + tl*32 + j] + p0*W[192*128+j] + p1*W[193*128+j];
    for (int k = 0; k < 64; k++){
        float a = ws[HF_OFF + (size_t)k*N + node];
        const float* wr = W + (size_t)k*128;
        #pragma unroll
        for (int j = 0; j < 32; j++) acc[j] = fmaf(a, wr[j], acc[j]);
    }
    for (int k = 0; k < 64; k++){
        float a = ws[MTF_OFF + (size_t)k*N + node];
        const float* wr = W + (size_t)(64+k)*128;
        #pragma unroll
        for (int j = 0; j < 32; j++) acc[j] = fmaf(a, wr[j], acc[j]);
    }
    for (int k = 0; k < 64; k++){
        float a = ws[MFF_OFF + (size_t)k*N + node];
        const float* wr = W + (size_t)(128+k)*128;
        #pragma unroll
        for (int j = 0; j < 32; j++) acc[j] = fmaf(a, wr[j], acc[j]);
    }
    if (ch == 0){
        #pragma unroll
        for (int j = 0; j < 32; j++)
            ws[AL_OFF + (size_t)(tl*32+j)*N + node] = sigm(acc[j]);
    } else {
        #pragma unroll
        for (int j = 0; j < 32; j++){
            int row = tl*32+j;
            ws[RH_OFF + (size_t)row*N + node] = sigm(acc[j]) * ws[HF_OFF + (size_t)row*N + node];
        }
    }
}

// ---- gate corr + state update (Dirichlet fused) ----
__global__ __launch_bounds__(256) void gate_corr(const int* __restrict__ tags,
                                                 float* __restrict__ ws){
    int node = blockIdx.x * 256 + threadIdx.x;
    if (node >= N) return;
    int tl = blockIdx.y, j0 = tl*32;
    const float* W = ws + CW_OFF + j0;   // + k*64 + j
    float p0 = ws[PRB0_OFF+node], p1 = ws[PRB1_OFF+node];
    float acc[32];
    #pragma unroll
    for (int j = 0; j < 32; j++)
        acc[j] = ws[CB_OFF + j0 + j] + p0*W[192*64+j] + p1*W[193*64+j];
    for (int k = 0; k < 64; k++){
        float a = ws[RH_OFF + (size_t)k*N + node];
        const float* wr = W + (size_t)k*64;
        #pragma unroll
        for (int j = 0; j < 32; j++) acc[j] = fmaf(a, wr[j], acc[j]);
    }
    for (int k = 0; k < 64; k++){
        float a = ws[MTF_OFF + (size_t)k*N + node];
        const float* wr = W + (size_t)(64+k)*64;
        #pragma unroll
        for (int j = 0; j < 32; j++) acc[j] = fmaf(a, wr[j], acc[j]);
    }
    for (int k = 0; k < 64; k++){
        float a = ws[MFF_OFF + (size_t)k*N + node];
        const float* wr = W + (size_t)(128+k)*64;
        #pragma unroll
        for (int j = 0; j < 32; j++) acc[j] = fmaf(a, wr[j], acc[j]);
    }
    int tg = tags[node];
    #pragma unroll
    for (int j = 0; j < 32; j++){
        size_t off = (size_t)(j0+j)*N + node;
        float hn = fmaf(ws[AL_OFF+off], tanhf(acc[j]), ws[HF_OFF+off]);
        if (tg == 1) hn = ws[H0F_OFF+off];
        ws[HF_OFF+off] = hn;
    }
}

// ---- decode stage 1: T1 = relu(H @ dW1 + db1), feature-major (src param) ----
__global__ __launch_bounds__(256) void dec1(const float* __restrict__ src,
                                            float* __restrict__ dst,
                                            float* __restrict__ ws){
    int node = blockIdx.x * 256 + threadIdx.x;
    if (node >= N) return;
    int j0 = blockIdx.y * 32;
    float acc[32];
    #pragma unroll
    for (int j = 0; j < 32; j++) acc[j] = ws[DB1_OFF + j0 + j];
    for (int k = 0; k < 64; k++){
        float a = src[(size_t)k*N + node];
        const float* wr = ws + DW1_OFF + (size_t)k*64 + j0;
        #pragma unroll
        for (int j = 0; j < 32; j++) acc[j] = fmaf(a, wr[j], acc[j]);
    }
    #pragma unroll
    for (int j = 0; j < 32; j++)
        dst[(size_t)(j0+j)*N + node] = fmaxf(acc[j], 0.f);
}

// ---- decode stage 2 + encode(u) + enc loss ----
__global__ __launch_bounds__(256) void enc_u(int step, float* __restrict__ ws){
    int node = blockIdx.x * 256 + threadIdx.x;
    float encA = 0.f;
    if (node < N){
        int j0 = blockIdx.y * 32;
        float u = ws[DB2_OFF];
        for (int j = 0; j < 64; j++)
            u = fmaf(ws[T1_OFF + (size_t)j*N + node], ws[DW2_OFF+j], u);
        if (blockIdx.y == 0) ws[UV_OFF+node] = u;
        float acc[32];
        #pragma unroll
        for (int j = 0; j < 32; j++) acc[j] = ws[EB2_OFF + j0 + j];
        for (int k = 0; k < 64; k++){
            float t = fmaxf(fmaf(u, ws[EW1_OFF+k], ws[EB1_OFF+k]), 0.f);
            const float* wr = ws + EW2_OFF + (size_t)k*64 + j0;
            #pragma unroll
            for (int j = 0; j < 32; j++) acc[j] = fmaf(t, wr[j], acc[j]);
        }
        #pragma unroll
        for (int j = 0; j < 32; j++){
            size_t off = (size_t)(j0+j)*N + node;
            ws[EV_OFF+off] = acc[j];
            float d = acc[j] - ws[HF_OFF+off];
            encA += d*d;
        }
    }
    encA = wave_sum(encA);
    if ((threadIdx.x & 63) == 0) atomicAdd(&ws[LOSS_OFF + step*3 + 1], encA);
}

// ---- final: u2 = dec(E), auto loss, residual CSR, res loss ----
__global__ __launch_bounds__(256) void aux_res(int step, const int* __restrict__ ei,
                                               const void* __restrict__ aij,
                                               const void* __restrict__ y,
                                               float* __restrict__ ws){
    const int* wsI = (const int*)ws;
    int node = blockIdx.x * 256 + threadIdx.x;
    bool isbf = ws[FLAG_OFF] > 0.5f;
    float autoA = 0.f, resA = 0.f;
    if (node < N){
        float u2 = ws[DB2_OFF];
        for (int j = 0; j < 64; j++)
            u2 = fmaf(ws[T1_OFF + (size_t)j*N + node], ws[DW2_OFF+j], u2);
        float u = ws[UV_OFF+node];
        float ad = u2 - u;
        autoA = ad*ad;
        float acc = 0.f;
        int beg = wsI[RP_OFF+node], end = wsI[RP_OFF+node+1];
        for (int j = beg; j < end; j++){
            int e = wsI[RIDX_OFF+j];
            acc = fmaf(ldv(aij, e, isbf), ws[UV_OFF + ei[E+e]], acc);
        }
        float d = acc - ldv(y, node, isbf);
        resA = d*d;
    }
    autoA = wave_sum(autoA);
    resA = wave_sum(resA);
    if ((threadIdx.x & 63) == 0){
        atomicAdd(&ws[LOSS_OFF + step*3 + 2], autoA);
        atomicAdd(&ws[LOSS_OFF + step*3], resA);
    }
}

// ---- output writer ----
__global__ __launch_bounds__(256) void write_out(void* __restrict__ outp,
                                                 const float* __restrict__ ws){
    int i = blockIdx.x * 256 + threadIdx.x;
    if (i > N) return;
    bool isbf = ws[FLAG_OFF] > 0.5f;
    float v;
    if (i < N){
        v = ws[UV_OFF+i];
    } else {
        const float* L = ws + LOSS_OFF;
        float inv = 1.f / (float)N, invl = 1.f / ((float)N * 64.f);
        v = 0.9f*L[0]*inv + L[1]*invl + L[2]*inv
          +      L[3]*inv + L[4]*invl + L[5]*inv;
    }
    if (isbf) ((unsigned short*)outp)[i] = f2b(v);
    else      ((float*)outp)[i] = v;
}

extern "C" void kernel_launch(void* const* d_in, const int* in_sizes, int n_in,
                              void* d_out, int out_size, void* d_ws, size_t ws_size,
                              hipStream_t stream){
    const void* x    = d_in[0];
    const void* y    = d_in[2];
    const int* tags  = (const int*)d_in[3];
    const int* ei    = (const int*)d_in[4];
    const void* attr = d_in[5];
    const void* aij  = d_in[6];
    const void* prb  = d_in[7];
    WPtrs P;
    P.ptW1 = d_in[8];  P.ptb1 = d_in[9];  P.ptW2 = d_in[10]; P.ptb2 = d_in[11];
    P.pfW1 = d_in[12]; P.pfb1 = d_in[13]; P.pfW2 = d_in[14]; P.pfb2 = d_in[15];
    P.zkW  = d_in[16]; P.zkb  = d_in[17]; P.rkW  = d_in[18]; P.rkb  = d_in[19];
    P.cW   = d_in[20]; P.cb   = d_in[21];
    P.eW1  = d_in[22]; P.eb1  = d_in[23]; P.eW2  = d_in[24]; P.eb2  = d_in[25];
    P.dW1  = d_in[26]; P.db1  = d_in[27]; P.dW2  = d_in[28]; P.db2  = d_in[29];
    float* ws = (float*)d_ws;
    int* wsI = (int*)d_ws;

    detect_kernel<<<1, 256, 0, stream>>>(y, ws);
    prep_kernel<<<(PREP_TOTAL + 255)/256, 256, 0, stream>>>(P, ws);
    prb_split<<<196, 256, 0, stream>>>(prb, ws);
    zero_deg<<<196, 256, 0, stream>>>(wsI);
    hist_kernel<<<E/256, 256, 0, stream>>>(ei, wsI);
    scan1<<<dim3(196, 2), 256, 0, stream>>>(wsI);
    scan2<<<dim3(1, 2), 256, 0, stream>>>(wsI);
    scan3<<<dim3(196, 2), 256, 0, stream>>>(wsI);
    scatter_kernel<<<E/256, 256, 0, stream>>>(ei, wsI);
    encode_init<<<dim3(196, 2), 256, 0, stream>>>(x, ws);
    for (int step = 0; step < 2; step++){
        // mess_to: aggregate at col; other end = row
        node_pre<<<(N*64)/256, 256, 0, stream>>>(ws + PT1_OFF, ws);
        gather_msgs<<<1024, 256, 0, stream>>>(wsI + CP_OFF, wsI + CIDX_OFF, ei, attr,
                                              ws + AT_OFF, ws + BT1_OFF, ws + WT2_OFF, ws + BT2_OFF, ws);
        transpose_msg<<<782, 256, 0, stream>>>(ws + PA_OFF, ws + MTF_OFF);
        // mess_from: aggregate at row; other end = col
        node_pre<<<(N*64)/256, 256, 0, stream>>>(ws + PF1_OFF, ws);
        gather_msgs<<<1024, 256, 0, stream>>>(wsI + RP_OFF, wsI + RIDX_OFF, ei + E, attr,
                                              ws + AF_OFF, ws + BF1_OFF, ws + WF2_OFF, ws + BF2_OFF, ws);
        transpose_msg<<<782, 256, 0, stream>>>(ws + PA_OFF, ws + MFF_OFF);
        gate_zr<<<dim3(196, 4), 256, 0, stream>>>(ws);
        gate_corr<<<dim3(196, 2), 256, 0, stream>>>(tags, ws);
        dec1<<<dim3(196, 2), 256, 0, stream>>>(ws + HF_OFF, ws + T1_OFF, ws);
        enc_u<<<dim3(196, 2), 256, 0, stream>>>(step, ws);
        dec1<<<dim3(196, 2), 256, 0, stream>>>(ws + EV_OFF, ws + T1_OFF, ws);
        aux_res<<<196, 256, 0, stream>>>(step, ei, aij, y, ws);
    }
    write_out<<<197, 256, 0, stream>>>(d_out, ws);
}

// Round 6
// 1614.717 us; speedup vs baseline: 8.8565x; 1.0236x over previous
//
#include <hip/hip_runtime.h>

#define DEV __device__ __forceinline__

constexpr int N = 50000;
constexpr int E = 800000;

// ---- float region (4-byte units) ----
constexpr int HF_OFF  = 0;                  // 64N f32  H  [feat][node]
constexpr int H0F_OFF = 64*N;               // 64N f32  H0
constexpr int MTF_OFF = 128*N;              // 32N (bf16 ushort [feat][node])
constexpr int MFF_OFF = 160*N;              // 32N (bf16)
// R1 (128N), phase-dependent:
//   setup:    EREC uint4[E] staging (4E = 3.2M <= 6.4M)
//   messages: PAT (64N f32) | PAF (64N f32)   (gather writes msg in place)
//   gate:     AL (64N f32)  | RH (64N f32)
//   decode:   T1 (64N f32)  | EV (64N f32)
constexpr int R1_OFF  = 192*N;
constexpr int PAT_OFF = R1_OFF;
constexpr int PAF_OFF = R1_OFF + 64*N;
constexpr int ER_OFF  = R1_OFF;             // uint4[E] staging
constexpr int AL_OFF  = R1_OFF;
constexpr int RH_OFF  = R1_OFF + 64*N;
constexpr int T1_OFF  = R1_OFF;
constexpr int EV_OFF  = R1_OFF + 64*N;
// R2 (64N), phase-dependent:
//   setup: CIDX (E) | RIDX (E)    (2E = 1.6M <= 3.2M)
//   steps: PBT bf16 (32N) | PBF bf16 (32N)
constexpr int R2_OFF   = 320*N;
constexpr int CIDX_OFF = R2_OFF;
constexpr int RIDX_OFF = R2_OFF + E;
constexpr int PBT_OFF  = R2_OFF;
constexpr int PBF_OFF  = R2_OFF + 32*N;
constexpr int UV_OFF   = 384*N;             // N
constexpr int LOSS_OFF = UV_OFF + N;        // 6 + pad + flag
constexpr int FLAG_OFF = LOSS_OFF + 7;
// weights (f32 copies)
constexpr int WZR_OFF = LOSS_OFF + 8;       // 194*128
constexpr int GB_OFF  = WZR_OFF + 24832;    // 128
constexpr int CW_OFF  = GB_OFF + 128;       // 12416
constexpr int CB_OFF  = CW_OFF + 12416;     // 64
constexpr int PT1_OFF = CB_OFF + 64;        // 8192
constexpr int AT_OFF  = PT1_OFF + 8192;     // 192
constexpr int BT1_OFF = AT_OFF + 192;       // 64
constexpr int WT2_OFF = BT1_OFF + 64;       // 4096
constexpr int BT2_OFF = WT2_OFF + 4096;     // 64
constexpr int PF1_OFF = BT2_OFF + 64;       // 8192
constexpr int AF_OFF  = PF1_OFF + 8192;     // 192
constexpr int BF1_OFF = AF_OFF + 192;       // 64
constexpr int WF2_OFF = BF1_OFF + 64;       // 4096
constexpr int BF2_OFF = WF2_OFF + 4096;     // 64
constexpr int DW1_OFF = BF2_OFF + 64;       // 4096
constexpr int DW2_OFF = DW1_OFF + 4096;     // 64
constexpr int DB1_OFF = DW2_OFF + 64;       // 64
constexpr int DB2_OFF = DB1_OFF + 64;       // 1 (+3)
constexpr int EW1_OFF = DB2_OFF + 4;        // 64
constexpr int EB1_OFF = EW1_OFF + 64;       // 64
constexpr int EW2_OFF = EB1_OFF + 64;       // 4096
constexpr int EB2_OFF = EW2_OFF + 4096;     // 64
constexpr int PRB0_OFF = EB2_OFF + 64;      // N
constexpr int PRB1_OFF = PRB0_OFF + N;      // N
constexpr int FEND    = PRB1_OFF + N;
// CSR-ordered edge records (persistent)
constexpr int CO_OFF  = FEND;               // E ints   (other = row, col-CSR order)
constexpr int CAW_OFF = CO_OFF + E;         // uint2[E] (a01, a2|aij)
constexpr int RO_OFF  = CAW_OFF + 2*E;      // E ints   (other = col, row-CSR order)
constexpr int RAW_OFF = RO_OFF + E;         // uint2[E]
constexpr int CP_OFF  = RAW_OFF + 2*E;      // N+1
constexpr int RP_OFF  = CP_OFF + N + 1;     // N+1
constexpr int CF_OFF  = RP_OFF + N + 1;     // N (deg then fill)
constexpr int RF_OFF  = CF_OFF + N;         // N
constexpr int BS_OFF  = RF_OFF + N;         // 512
constexpr int BO_OFF  = BS_OFF + 512;       // 512  (total ~97.7 MB)

constexpr int PREP_TOTAL = 24832+128+12416+64+8192+192+64+4096+64+8192+192+64+4096+64+4096+64+64+1+64+64+4096+64+6;

DEV float b2f(unsigned short u){ return __uint_as_float(((unsigned)u) << 16); }
DEV unsigned short f2b(float f){
    unsigned u = __float_as_uint(f);
    return (unsigned short)((u + 0x7fffu + ((u >> 16) & 1u)) >> 16);
}
DEV float blo(unsigned u){ return __uint_as_float(u << 16); }
DEV float bhi(unsigned u){ return __uint_as_float(u & 0xffff0000u); }
DEV float bcastf(float v, int k){
    return __uint_as_float(__builtin_amdgcn_readlane(__float_as_uint(v), k));
}
DEV int bcasti(int v, int k){ return __builtin_amdgcn_readlane(v, k); }
DEV float wave_sum(float v){
    #pragma unroll
    for (int off = 32; off > 0; off >>= 1) v += __shfl_xor(v, off, 64);
    return v;
}
DEV float ldv(const void* p, int i, bool isbf){
    return isbf ? b2f(((const unsigned short*)p)[i]) : ((const float*)p)[i];
}
DEV unsigned short ld16(const void* p, int i, bool isbf){
    return isbf ? ((const unsigned short*)p)[i] : f2b(((const float*)p)[i]);
}
DEV float sigm(float x){ return 1.f / (1.f + __expf(-x)); }

struct WPtrs {
    const void *ptW1, *ptb1, *ptW2, *ptb2;
    const void *pfW1, *pfb1, *pfW2, *pfb2;
    const void *zkW, *zkb, *rkW, *rkb, *cW, *cb;
    const void *eW1, *eb1, *eW2, *eb2;
    const void *dW1, *db1, *dW2, *db2;
};

// ---- dtype detection ----
__global__ __launch_bounds__(256) void detect_kernel(const void* y, float* __restrict__ ws){
    __shared__ int bad;
    if (threadIdx.x == 0) bad = 0;
    __syncthreads();
    const unsigned short* yy = (const unsigned short*)y;
    int mybad = 0;
    for (int i = threadIdx.x; i < 4096; i += 256){
        float v = b2f(yy[i]);
        if (!(v > -1.0e6f && v < 1.0e6f)) mybad = 1;
    }
    if (mybad) bad = 1;
    __syncthreads();
    if (threadIdx.x == 0) ws[FLAG_OFF] = bad ? 0.0f : 1.0f;
}

// ---- weight prep ----
__global__ __launch_bounds__(256) void prep_kernel(WPtrs P, float* __restrict__ ws){
    int j = blockIdx.x * 256 + threadIdx.x;
    if (j >= PREP_TOTAL) return;
    bool isbf = ws[FLAG_OFF] > 0.5f;
    if (j < 24832){
        int k = j >> 7, c = j & 127;
        ws[WZR_OFF+j] = (c < 64) ? ldv(P.zkW, k*64+c, isbf) : ldv(P.rkW, k*64+(c-64), isbf);
        return;
    } j -= 24832;
    if (j < 128){ ws[GB_OFF+j] = (j < 64) ? ldv(P.zkb, j, isbf) : ldv(P.rkb, j-64, isbf); return; } j -= 128;
    if (j < 12416){ ws[CW_OFF+j] = ldv(P.cW, j, isbf); return; } j -= 12416;
    if (j < 64){ ws[CB_OFF+j] = ldv(P.cb, j, isbf); return; } j -= 64;
    if (j < 8192){ ws[PT1_OFF+j] = ldv(P.ptW1, j, isbf); return; } j -= 8192;
    if (j < 192){ ws[AT_OFF+j] = ldv(P.ptW1, 128*64+j, isbf); return; } j -= 192;
    if (j < 64){ ws[BT1_OFF+j] = ldv(P.ptb1, j, isbf); return; } j -= 64;
    if (j < 4096){ ws[WT2_OFF+j] = ldv(P.ptW2, j, isbf); return; } j -= 4096;
    if (j < 64){ ws[BT2_OFF+j] = ldv(P.ptb2, j, isbf); return; } j -= 64;
    if (j < 8192){ ws[PF1_OFF+j] = ldv(P.pfW1, j, isbf); return; } j -= 8192;
    if (j < 192){ ws[AF_OFF+j] = ldv(P.pfW1, 128*64+j, isbf); return; } j -= 192;
    if (j < 64){ ws[BF1_OFF+j] = ldv(P.pfb1, j, isbf); return; } j -= 64;
    if (j < 4096){ ws[WF2_OFF+j] = ldv(P.pfW2, j, isbf); return; } j -= 4096;
    if (j < 64){ ws[BF2_OFF+j] = ldv(P.pfb2, j, isbf); return; } j -= 64;
    if (j < 4096){ ws[DW1_OFF+j] = ldv(P.dW1, j, isbf); return; } j -= 4096;
    if (j < 64){ ws[DW2_OFF+j] = ldv(P.dW2, j, isbf); return; } j -= 64;
    if (j < 64){ ws[DB1_OFF+j] = ldv(P.db1, j, isbf); return; } j -= 64;
    if (j < 1){ ws[DB2_OFF] = ldv(P.db2, 0, isbf); return; } j -= 1;
    if (j < 64){ ws[EW1_OFF+j] = ldv(P.eW1, j, isbf); return; } j -= 64;
    if (j < 64){ ws[EB1_OFF+j] = ldv(P.eb1, j, isbf); return; } j -= 64;
    if (j < 4096){ ws[EW2_OFF+j] = ldv(P.eW2, j, isbf); return; } j -= 4096;
    if (j < 64){ ws[EB2_OFF+j] = ldv(P.eb2, j, isbf); return; } j -= 64;
    ws[LOSS_OFF+j] = 0.f;
}

__global__ __launch_bounds__(256) void prb_split(const void* __restrict__ prb, float* __restrict__ ws){
    int i = blockIdx.x * 256 + threadIdx.x;
    if (i >= N) return;
    bool isbf = ws[FLAG_OFF] > 0.5f;
    ws[PRB0_OFF+i] = ldv(prb, 2*i,   isbf);
    ws[PRB1_OFF+i] = ldv(prb, 2*i+1, isbf);
}

// ---- CSR build ----
__global__ __launch_bounds__(256) void zero_deg(int* __restrict__ wsI){
    int i = blockIdx.x * 256 + threadIdx.x;
    if (i < N){ wsI[CF_OFF+i] = 0; wsI[RF_OFF+i] = 0; }
}
// pack 16B edge record + degree histogram
__global__ __launch_bounds__(256) void pack_hist(const int* __restrict__ ei,
                                                 const void* __restrict__ attr,
                                                 const void* __restrict__ aij,
                                                 float* __restrict__ ws){
    int e = blockIdx.x * 256 + threadIdx.x;
    if (e >= E) return;
    int* wsI = (int*)ws;
    bool isbf = ws[FLAG_OFF] > 0.5f;
    int r = ei[e], c = ei[E+e];
    unsigned a01 = (unsigned)ld16(attr, 3*e, isbf) | ((unsigned)ld16(attr, 3*e+1, isbf) << 16);
    unsigned a2w = (unsigned)ld16(attr, 3*e+2, isbf) | ((unsigned)ld16(aij, e, isbf) << 16);
    ((uint4*)(ws + ER_OFF))[e] = make_uint4((unsigned)r, (unsigned)c, a01, a2w);
    atomicAdd(&wsI[RF_OFF + r], 1);
    atomicAdd(&wsI[CF_OFF + c], 1);
}
__global__ __launch_bounds__(256) void scan1(int* __restrict__ wsI){
    int y = blockIdx.y;
    const int* deg = wsI + (y ? RF_OFF : CF_OFF);
    int* tmp = wsI + (y ? RP_OFF : CP_OFF);
    int i = blockIdx.x * 256 + threadIdx.x;
    __shared__ int sh[256];
    int v = (i < N) ? deg[i] : 0;
    sh[threadIdx.x] = v;
    __syncthreads();
    #pragma unroll
    for (int off = 1; off < 256; off <<= 1){
        int t = (threadIdx.x >= (unsigned)off) ? sh[threadIdx.x - off] : 0;
        __syncthreads();
        sh[threadIdx.x] += t;
        __syncthreads();
    }
    if (i < N) tmp[i] = sh[threadIdx.x] - v;
    if (threadIdx.x == 255) wsI[BS_OFF + y*256 + blockIdx.x] = sh[255];
}
__global__ __launch_bounds__(256) void scan2(int* __restrict__ wsI){
    int y = blockIdx.y, t = threadIdx.x;
    __shared__ int sh[256];
    int v = (t < 196) ? wsI[BS_OFF + y*256 + t] : 0;
    sh[t] = v;
    __syncthreads();
    #pragma unroll
    for (int off = 1; off < 256; off <<= 1){
        int u = (t >= (unsigned)off) ? sh[t - off] : 0;
        __syncthreads();
        sh[t] += u;
        __syncthreads();
    }
    wsI[BO_OFF + y*256 + t] = sh[t] - v;
}
__global__ __launch_bounds__(256) void scan3(int* __restrict__ wsI){
    int y = blockIdx.y;
    int* ptr  = wsI + (y ? RP_OFF : CP_OFF);
    int* fill = wsI + (y ? RF_OFF : CF_OFF);
    int i = blockIdx.x * 256 + threadIdx.x;
    if (i < N){
        int p = ptr[i] + wsI[BO_OFF + y*256 + blockIdx.x];
        ptr[i] = p; fill[i] = p;
    }
    if (blockIdx.x == 0 && threadIdx.x == 0) ptr[N] = E;
}
__global__ __launch_bounds__(256) void scatter_kernel(float* __restrict__ ws){
    int e = blockIdx.x * 256 + threadIdx.x;
    if (e >= E) return;
    int* wsI = (int*)ws;
    uint4 rec = ((const uint4*)(ws + ER_OFF))[e];
    int q = atomicAdd(&wsI[RF_OFF + (int)rec.x], 1);
    wsI[RIDX_OFF + q] = e;
    int p = atomicAdd(&wsI[CF_OFF + (int)rec.y], 1);
    wsI[CIDX_OFF + p] = e;
}
// lay records out in CSR order (parallel arrays, fully coalesced gather reads)
__global__ __launch_bounds__(256) void reorder_kernel(float* __restrict__ ws){
    int p = blockIdx.x * 256 + threadIdx.x;
    if (p >= E) return;
    const int* wsI = (const int*)ws;
    const uint4* erec = (const uint4*)(ws + ER_OFF);
    if (blockIdx.y == 0){
        uint4 rec = erec[wsI[CIDX_OFF + p]];
        ((int*)(ws + CO_OFF))[p] = (int)rec.x;                 // other = row
        ((uint2*)(ws + CAW_OFF))[p] = make_uint2(rec.z, rec.w);
    } else {
        uint4 rec = erec[wsI[RIDX_OFF + p]];
        ((int*)(ws + RO_OFF))[p] = (int)rec.y;                 // other = col
        ((uint2*)(ws + RAW_OFF))[p] = make_uint2(rec.z, rec.w);
    }
}

// ---- encoder: HF/H0F feature-major f32, thread per node, j-tile 32 ----
__global__ __launch_bounds__(256) void encode_init(const void* __restrict__ x,
                                                   float* __restrict__ ws){
    int node = blockIdx.x * 256 + threadIdx.x;
    if (node >= N) return;
    bool isbf = ws[FLAG_OFF] > 0.5f;
    int j0 = blockIdx.y * 32;
    float xv = ldv(x, node, isbf);
    float acc[32];
    #pragma unroll
    for (int j = 0; j < 32; j++) acc[j] = ws[EB2_OFF + j0 + j];
    for (int k = 0; k < 64; k++){
        float t = fmaxf(fmaf(xv, ws[EW1_OFF+k], ws[EB1_OFF+k]), 0.f);
        const float* wr = ws + EW2_OFF + (size_t)k*64 + j0;
        #pragma unroll
        for (int j = 0; j < 32; j++) acc[j] = fmaf(t, wr[j], acc[j]);
    }
    #pragma unroll
    for (int j = 0; j < 32; j++){
        ws[H0F_OFF + (size_t)(j0+j)*N + node] = acc[j];
        ws[HF_OFF  + (size_t)(j0+j)*N + node] = acc[j];
    }
}

// ---- per-direction first-layer precompute (PA f32, PB bf16; node-major) ----
__global__ __launch_bounds__(256) void node_pre(float* __restrict__ ws){
    int idx = blockIdx.x * 256 + threadIdx.x;
    if (idx >= N*64) return;
    int dir = blockIdx.y;
    int node = idx >> 6, f = idx & 63;
    const float* W1 = ws + (dir ? PF1_OFF : PT1_OFF);
    float* paOut = ws + (dir ? PAF_OFF : PAT_OFF);
    unsigned short* pbOut = (unsigned short*)(ws + (dir ? PBF_OFF : PBT_OFF));
    float aA = 0.f, aB = 0.f;
    for (int k = 0; k < 64; k++){
        float hv = ws[HF_OFF + (size_t)k*N + node];
        aA = fmaf(hv, W1[k*64+f],      aA);
        aB = fmaf(hv, W1[(64+k)*64+f], aB);
    }
    paOut[idx] = aA;
    pbOut[idx] = f2b(aB);
}

// ---- CSR message gather: wave/node, lane=feature, 8-deep pipelined ----
__global__ __launch_bounds__(256) void gather_msgs(float* __restrict__ ws){
    int dir = blockIdx.y;
    const int* wsI = (const int*)ws;
    const int* csrPtr = wsI + (dir ? RP_OFF : CP_OFF);
    const int* co = (const int*)(ws + (dir ? RO_OFF : CO_OFF));
    const uint2* caw = (const uint2*)(ws + (dir ? RAW_OFF : CAW_OFF));
    float* pa = ws + (dir ? PAF_OFF : PAT_OFF);
    const unsigned short* pgb = (const unsigned short*)(ws + (dir ? PBF_OFF : PBT_OFF));
    const float* A3 = ws + (dir ? AF_OFF : AT_OFF);
    const float* b1 = ws + (dir ? BF1_OFF : BT1_OFF);
    const float* W2 = ws + (dir ? WF2_OFF : WT2_OFF);
    const float* b2 = ws + (dir ? BF2_OFF : BT2_OFF);

    int lane = threadIdx.x & 63;
    int wv = threadIdx.x >> 6;
    float W2c[64];
    #pragma unroll
    for (int k = 0; k < 64; k++) W2c[k] = W2[k*64 + lane];
    float A0 = A3[lane], A1 = A3[64+lane], A2 = A3[128+lane];
    float B1 = b1[lane], B2 = b2[lane];
    int gw = blockIdx.x * 4 + wv;
    int nw = gridDim.x * 4;
    for (int node = gw; node < N; node += nw){
        float pav = pa[(size_t)node*64 + lane];
        float hs = 0.f;
        int cnt = 0;
        int beg = csrPtr[node], end = csrPtr[node+1];
        for (int base = beg; base < end; base += 64){
            int mcnt = end - base; if (mcnt > 64) mcnt = 64;
            int oL = 0; unsigned aL = 0, wL = 0;
            if (lane < mcnt){
                oL = co[base + lane];
                uint2 cw = caw[base + lane];
                aL = cw.x; wL = cw.y;
            }
            for (int g = 0; g < mcnt; g += 8){
                int gcnt = mcnt - g; if (gcnt > 8) gcnt = 8;
                int oo[8]; float pb[8]; unsigned zz[8], wwv[8];
                #pragma unroll
                for (int t = 0; t < 8; t++){
                    if (t < gcnt){
                        oo[t] = bcasti(oL, g+t);
                        zz[t] = (unsigned)bcasti((int)aL, g+t);
                        wwv[t] = (unsigned)bcasti((int)wL, g+t);
                        pb[t] = b2f(pgb[(size_t)oo[t]*64 + lane]);
                    } else { oo[t] = node; pb[t] = 0.f; zz[t] = 0; wwv[t] = 0; }
                }
                #pragma unroll
                for (int t = 0; t < 8; t++){
                    float hv = pav + pb[t] + blo(zz[t])*A0 + bhi(zz[t])*A1 + blo(wwv[t])*A2 + B1;
                    if (oo[t] != node){ hs += fmaxf(hv, 0.f); cnt++; }
                }
            }
        }
        float m = (float)cnt * B2;
        #pragma unroll
        for (int k = 0; k < 64; k++) m = fmaf(bcastf(hs, k), W2c[k], m);
        pa[(size_t)node*64 + lane] = m;
    }
}

// ---- transpose msg [node][64] f32 -> [64][N] bf16 ----
__global__ __launch_bounds__(256) void transpose_msg(float* __restrict__ ws){
    __shared__ float t[64][65];
    const float* src = ws + (blockIdx.y ? PAF_OFF : PAT_OFF);
    unsigned short* dst = (unsigned short*)(ws + (blockIdx.y ? MFF_OFF : MTF_OFF));
    int n0 = blockIdx.x * 64;
    #pragma unroll
    for (int i = 0; i < 16; i++){
        int idx = i*256 + threadIdx.x;
        int nl = idx >> 6, f = idx & 63;
        int node = n0 + nl;
        t[nl][f] = (node < N) ? src[(size_t)node*64 + f] : 0.f;
    }
    __syncthreads();
    #pragma unroll
    for (int i = 0; i < 16; i++){
        int idx = i*256 + threadIdx.x;
        int fw = idx >> 6, nl = idx & 63;
        int node = n0 + nl;
        if (node < N) dst[(size_t)fw*N + node] = f2b(t[nl][fw]);
    }
}

// ---- gate z/r: thread per node, j-tile 32; RH = sigm(r)*H ----
__global__ __launch_bounds__(256) void gate_zr(float* __restrict__ ws){
    int node = blockIdx.x * 256 + threadIdx.x;
    if (node >= N) return;
    int ch = blockIdx.y >> 1, tl = blockIdx.y & 1;
    const float* W = ws + WZR_OFF + ch*64 + tl*32;
    const unsigned short* mtU = (const unsigned short*)(ws + MTF_OFF);
    const unsigned short* mfU = (const unsigned short*)(ws + MFF_OFF);
    float p0 = ws[PRB0_OFF+node], p1 = ws[PRB1_OFF+node];
    float acc[32];
    #pragma unroll
    for (int j = 0; j < 32; j++)
        acc[j] = ws[GB_OFF + ch*64 + tl*32 + j] + p0*W[192*128+j] + p1*W[193*128+j];
    for (int k = 0; k < 64; k++){
        float a = ws[HF_OFF + (size_t)k*N + node];
        const float* wr = W + (size_t)k*128;
        #pragma unroll
        for (int j = 0; j < 32; j++) acc[j] = fmaf(a, wr[j], acc[j]);
    }
    for (int k = 0; k < 64; k++){
        float a = b2f(mtU[(size_t)k*N + node]);
        const float* wr = W + (size_t)(64+k)*128;
        #pragma unroll
        for (int j = 0; j < 32; j++) acc[j] = fmaf(a, wr[j], acc[j]);
    }
    for (int k = 0; k < 64; k++){
        float a = b2f(mfU[(size_t)k*N + node]);
        const float* wr = W + (size_t)(128+k)*128;
        #pragma unroll
        for (int j = 0; j < 32; j++) acc[j] = fmaf(a, wr[j], acc[j]);
    }
    if (ch == 0){
        #pragma unroll
        for (int j = 0; j < 32; j++)
            ws[AL_OFF + (size_t)(tl*32+j)*N + node] = sigm(acc[j]);
    } else {
        #pragma unroll
        for (int j = 0; j < 32; j++){
            int row = tl*32+j;
            ws[RH_OFF + (size_t)row*N + node] = sigm(acc[j]) * ws[HF_OFF + (size_t)row*N + node];
        }
    }
}

// ---- gate corr + state update (Dirichlet fused) ----
__global__ __launch_bounds__(256) void gate_corr(const int* __restrict__ tags,
                                                 float* __restrict__ ws){
    int node = blockIdx.x * 256 + threadIdx.x;
    if (node >= N) return;
    int tl = blockIdx.y, j0 = tl*32;
    const float* W = ws + CW_OFF + j0;
    const unsigned short* mtU = (const unsigned short*)(ws + MTF_OFF);
    const unsigned short* mfU = (const unsigned short*)(ws + MFF_OFF);
    float p0 = ws[PRB0_OFF+node], p1 = ws[PRB1_OFF+node];
    float acc[32];
    #pragma unroll
    for (int j = 0; j < 32; j++)
        acc[j] = ws[CB_OFF + j0 + j] + p0*W[192*64+j] + p1*W[193*64+j];
    for (int k = 0; k < 64; k++){
        float a = ws[RH_OFF + (size_t)k*N + node];
        const float* wr = W + (size_t)k*64;
        #pragma unroll
        for (int j = 0; j < 32; j++) acc[j] = fmaf(a, wr[j], acc[j]);
    }
    for (int k = 0; k < 64; k++){
        float a = b2f(mtU[(size_t)k*N + node]);
        const float* wr = W + (size_t)(64+k)*64;
        #pragma unroll
        for (int j = 0; j < 32; j++) acc[j] = fmaf(a, wr[j], acc[j]);
    }
    for (int k = 0; k < 64; k++){
        float a = b2f(mfU[(size_t)k*N + node]);
        const float* wr = W + (size_t)(128+k)*64;
        #pragma unroll
        for (int j = 0; j < 32; j++) acc[j] = fmaf(a, wr[j], acc[j]);
    }
    int tg = tags[node];
    #pragma unroll
    for (int j = 0; j < 32; j++){
        size_t off = (size_t)(j0+j)*N + node;
        float hn = fmaf(ws[AL_OFF+off], tanhf(acc[j]), ws[HF_OFF+off]);
        if (tg == 1) hn = ws[H0F_OFF+off];
        ws[HF_OFF+off] = hn;
    }
}

// ---- decode stage 1: dst = relu(src @ dW1 + db1), feature-major ----
__global__ __launch_bounds__(256) void dec1(const float* __restrict__ src,
                                            float* __restrict__ dst,
                                            float* __restrict__ ws){
    int node = blockIdx.x * 256 + threadIdx.x;
    if (node >= N) return;
    int j0 = blockIdx.y * 32;
    float acc[32];
    #pragma unroll
    for (int j = 0; j < 32; j++) acc[j] = ws[DB1_OFF + j0 + j];
    for (int k = 0; k < 64; k++){
        float a = src[(size_t)k*N + node];
        const float* wr = ws + DW1_OFF + (size_t)k*64 + j0;
        #pragma unroll
        for (int j = 0; j < 32; j++) acc[j] = fmaf(a, wr[j], acc[j]);
    }
    #pragma unroll
    for (int j = 0; j < 32; j++)
        dst[(size_t)(j0+j)*N + node] = fmaxf(acc[j], 0.f);
}

// ---- decode stage 2 + encode(u) + enc loss ----
__global__ __launch_bounds__(256) void enc_u(int step, float* __restrict__ ws){
    int node = blockIdx.x * 256 + threadIdx.x;
    float encA = 0.f;
    if (node < N){
        int j0 = blockIdx.y * 32;
        float u = ws[DB2_OFF];
        for (int j = 0; j < 64; j++)
            u = fmaf(ws[T1_OFF + (size_t)j*N + node], ws[DW2_OFF+j], u);
        if (blockIdx.y == 0) ws[UV_OFF+node] = u;
        float acc[32];
        #pragma unroll
        for (int j = 0; j < 32; j++) acc[j] = ws[EB2_OFF + j0 + j];
        for (int k = 0; k < 64; k++){
            float t = fmaxf(fmaf(u, ws[EW1_OFF+k], ws[EB1_OFF+k]), 0.f);
            const float* wr = ws + EW2_OFF + (size_t)k*64 + j0;
            #pragma unroll
            for (int j = 0; j < 32; j++) acc[j] = fmaf(t, wr[j], acc[j]);
        }
        #pragma unroll
        for (int j = 0; j < 32; j++){
            size_t off = (size_t)(j0+j)*N + node;
            ws[EV_OFF+off] = acc[j];
            float d = acc[j] - ws[HF_OFF+off];
            encA += d*d;
        }
    }
    encA = wave_sum(encA);
    if ((threadIdx.x & 63) == 0) atomicAdd(&ws[LOSS_OFF + step*3 + 1], encA);
}

// ---- final: u2 = dec(E), auto loss, residual (row-CSR records), res loss ----
__global__ __launch_bounds__(256) void aux_res(int step, const void* __restrict__ y,
                                               float* __restrict__ ws){
    const int* wsI = (const int*)ws;
    int node = blockIdx.x * 256 + threadIdx.x;
    bool isbf = ws[FLAG_OFF] > 0.5f;
    float autoA = 0.f, resA = 0.f;
    if (node < N){
        float u2 = ws[DB2_OFF];
        for (int j = 0; j < 64; j++)
            u2 = fmaf(ws[T1_OFF + (size_t)j*N + node], ws[DW2_OFF+j], u2);
        float u = ws[UV_OFF+node];
        float ad = u2 - u;
        autoA = ad*ad;
        float acc = 0.f;
        int beg = wsI[RP_OFF+node], end = wsI[RP_OFF+node+1];
        const int* ro = (const int*)(ws + RO_OFF);
        const uint2* raw = (const uint2*)(ws + RAW_OFF);
        for (int p = beg; p < end; p++){
            int c = ro[p];
            float av = bhi(raw[p].y);   // aij (bf16)
            acc = fmaf(av, ws[UV_OFF + c], acc);
        }
        float d = acc - ldv(y, node, isbf);
        resA = d*d;
    }
    autoA = wave_sum(autoA);
    resA = wave_sum(resA);
    if ((threadIdx.x & 63) == 0){
        atomicAdd(&ws[LOSS_OFF + step*3 + 2], autoA);
        atomicAdd(&ws[LOSS_OFF + step*3], resA);
    }
}

// ---- output writer ----
__global__ __launch_bounds__(256) void write_out(void* __restrict__ outp,
                                                 const float* __restrict__ ws){
    int i = blockIdx.x * 256 + threadIdx.x;
    if (i > N) return;
    bool isbf = ws[FLAG_OFF] > 0.5f;
    float v;
    if (i < N){
        v = ws[UV_OFF+i];
    } else {
        const float* L = ws + LOSS_OFF;
        float inv = 1.f / (float)N, invl = 1.f / ((float)N * 64.f);
        v = 0.9f*L[0]*inv + L[1]*invl + L[2]*inv
          +      L[3]*inv + L[4]*invl + L[5]*inv;
    }
    if (isbf) ((unsigned short*)outp)[i] = f2b(v);
    else      ((float*)outp)[i] = v;
}

extern "C" void kernel_launch(void* const* d_in, const int* in_sizes, int n_in,
                              void* d_out, int out_size, void* d_ws, size_t ws_size,
                              hipStream_t stream){
    const void* x    = d_in[0];
    const void* y    = d_in[2];
    const int* tags  = (const int*)d_in[3];
    const int* ei    = (const int*)d_in[4];
    const void* attr = d_in[5];
    const void* aij  = d_in[6];
    const void* prb  = d_in[7];
    WPtrs P;
    P.ptW1 = d_in[8];  P.ptb1 = d_in[9];  P.ptW2 = d_in[10]; P.ptb2 = d_in[11];
    P.pfW1 = d_in[12]; P.pfb1 = d_in[13]; P.pfW2 = d_in[14]; P.pfb2 = d_in[15];
    P.zkW  = d_in[16]; P.zkb  = d_in[17]; P.rkW  = d_in[18]; P.rkb  = d_in[19];
    P.cW   = d_in[20]; P.cb   = d_in[21];
    P.eW1  = d_in[22]; P.eb1  = d_in[23]; P.eW2  = d_in[24]; P.eb2  = d_in[25];
    P.dW1  = d_in[26]; P.db1  = d_in[27]; P.dW2  = d_in[28]; P.db2  = d_in[29];
    float* ws = (float*)d_ws;
    int* wsI = (int*)d_ws;

    detect_kernel<<<1, 256, 0, stream>>>(y, ws);
    prep_kernel<<<(PREP_TOTAL + 255)/256, 256, 0, stream>>>(P, ws);
    prb_split<<<196, 256, 0, stream>>>(prb, ws);
    zero_deg<<<196, 256, 0, stream>>>(wsI);
    pack_hist<<<E/256, 256, 0, stream>>>(ei, attr, aij, ws);
    scan1<<<dim3(196, 2), 256, 0, stream>>>(wsI);
    scan2<<<dim3(1, 2), 256, 0, stream>>>(wsI);
    scan3<<<dim3(196, 2), 256, 0, stream>>>(wsI);
    scatter_kernel<<<E/256, 256, 0, stream>>>(ws);
    reorder_kernel<<<dim3(E/256, 2), 256, 0, stream>>>(ws);
    encode_init<<<dim3(196, 2), 256, 0, stream>>>(x, ws);
    for (int step = 0; step < 2; step++){
        node_pre<<<dim3((N*64)/256, 2), 256, 0, stream>>>(ws);
        gather_msgs<<<dim3(1024, 2), 256, 0, stream>>>(ws);
        transpose_msg<<<dim3(782, 2), 256, 0, stream>>>(ws);
        gate_zr<<<dim3(196, 4), 256, 0, stream>>>(ws);
        gate_corr<<<dim3(196, 2), 256, 0, stream>>>(tags, ws);
        dec1<<<dim3(196, 2), 256, 0, stream>>>(ws + HF_OFF, ws + T1_OFF, ws);
        enc_u<<<dim3(196, 2), 256, 0, stream>>>(step, ws);
        dec1<<<dim3(196, 2), 256, 0, stream>>>(ws + EV_OFF, ws + T1_OFF, ws);
        aux_res<<<196, 256, 0, stream>>>(step, y, ws);
    }
    write_out<<<197, 256, 0, stream>>>(d_out, ws);
}

// Round 7
// 1430.052 us; speedup vs baseline: 10.0002x; 1.1291x over previous
//
#include <hip/hip_runtime.h>

#define DEV __device__ __forceinline__

constexpr int N = 50000;
constexpr int E = 800000;

// ---- float region (4-byte units) ----
constexpr int HF_OFF  = 0;                  // 64N f32  H  [feat][node]
constexpr int H0F_OFF = 64*N;               // 64N f32  H0
constexpr int MTF_OFF = 128*N;              // bf16 [64][N] (32N floats)
constexpr int MFF_OFF = 160*N;              // bf16
// R1 (128N), phase-dependent: PAT|PAF ; AL|RH ; T1|EV
constexpr int R1_OFF  = 192*N;
constexpr int PAT_OFF = R1_OFF;
constexpr int PAF_OFF = R1_OFF + 64*N;
constexpr int AL_OFF  = R1_OFF;
constexpr int RH_OFF  = R1_OFF + 64*N;
constexpr int T1_OFF  = R1_OFF;
constexpr int EV_OFF  = R1_OFF + 64*N;
// R2: PBT bf16 (32N) | PBF bf16 (32N)
constexpr int PBT_OFF  = 320*N;
constexpr int PBF_OFF  = 352*N;
constexpr int UV_OFF   = 384*N;             // N
constexpr int LOSS_OFF = UV_OFF + N;        // 6 + pad + flag
constexpr int FLAG_OFF = LOSS_OFF + 7;
// weights (f32 copies)
constexpr int WZR_OFF = LOSS_OFF + 8;       // 194*128
constexpr int GB_OFF  = WZR_OFF + 24832;    // 128
constexpr int CW_OFF  = GB_OFF + 128;       // 12416
constexpr int CB_OFF  = CW_OFF + 12416;     // 64
constexpr int PT1_OFF = CB_OFF + 64;        // 8192
constexpr int AT_OFF  = PT1_OFF + 8192;     // 192
constexpr int BT1_OFF = AT_OFF + 192;       // 64
constexpr int WT2_OFF = BT1_OFF + 64;       // 4096
constexpr int BT2_OFF = WT2_OFF + 4096;     // 64
constexpr int PF1_OFF = BT2_OFF + 64;       // 8192
constexpr int AF_OFF  = PF1_OFF + 8192;     // 192
constexpr int BF1_OFF = AF_OFF + 192;       // 64
constexpr int WF2_OFF = BF1_OFF + 64;       // 4096
constexpr int BF2_OFF = WF2_OFF + 4096;     // 64
constexpr int DW1_OFF = BF2_OFF + 64;       // 4096
constexpr int DW2_OFF = DW1_OFF + 4096;     // 64
constexpr int DB1_OFF = DW2_OFF + 64;       // 64
constexpr int DB2_OFF = DB1_OFF + 64;       // 1 (+3)
constexpr int EW1_OFF = DB2_OFF + 4;        // 64
constexpr int EB1_OFF = EW1_OFF + 64;       // 64
constexpr int EW2_OFF = EB1_OFF + 64;       // 4096
constexpr int EB2_OFF = EW2_OFF + 4096;     // 64
constexpr int PRB0_OFF = EB2_OFF + 64;      // N
constexpr int PRB1_OFF = PRB0_OFF + N;      // N
constexpr int FEND    = PRB1_OFF + N;
// edge records (persistent, CSR-ordered, written directly by scatter)
constexpr int CREC_OFF = FEND;              // uint2[E]: msg-to   (live, col-CSR)
constexpr int RREC_OFF = CREC_OFF + 2*E;    // uint2[E]: msg-from (live, row-CSR)
constexpr int AREC_OFF = RREC_OFF + 2*E;    // uint[E]:  resid    (full, row-CSR) col|aij
constexpr int LCP_OFF  = AREC_OFF + E;      // N+1 live col ptr
constexpr int LRP_OFF  = LCP_OFF + N + 1;   // N+1 live row ptr
constexpr int FRP_OFF  = LRP_OFF + N + 1;   // N+1 full row ptr
constexpr int LCF_OFF  = FRP_OFF + N + 1;   // N fills
constexpr int LRF_OFF  = LCF_OFF + N;
constexpr int FRF_OFF  = LRF_OFF + N;
constexpr int CDEG_OFF = FRF_OFF + N;       // N
constexpr int RDEG_OFF = CDEG_OFF + N;      // N
constexpr int SDEG_OFF = RDEG_OFF + N;      // N (self-loop count)
constexpr int BS_OFF   = SDEG_OFF + N;      // 768
constexpr int BO_OFF   = BS_OFF + 768;      // 768   total ~95.7 MB

constexpr int PREP_TOTAL = 24832+128+12416+64+8192+192+64+4096+64+8192+192+64+4096+64+4096+64+64+1+64+64+4096+64+6;

DEV float b2f(unsigned short u){ return __uint_as_float(((unsigned)u) << 16); }
DEV unsigned short f2b(float f){
    unsigned u = __float_as_uint(f);
    return (unsigned short)((u + 0x7fffu + ((u >> 16) & 1u)) >> 16);
}
DEV float blo(unsigned u){ return __uint_as_float(u << 16); }
DEV float bhi(unsigned u){ return __uint_as_float(u & 0xffff0000u); }
DEV float bcastf(float v, int k){
    return __uint_as_float(__builtin_amdgcn_readlane(__float_as_uint(v), k));
}
DEV int bcasti(int v, int k){ return __builtin_amdgcn_readlane(v, k); }
DEV float wave_sum(float v){
    #pragma unroll
    for (int off = 32; off > 0; off >>= 1) v += __shfl_xor(v, off, 64);
    return v;
}
DEV float ldv(const void* p, int i, bool isbf){
    return isbf ? b2f(((const unsigned short*)p)[i]) : ((const float*)p)[i];
}
DEV unsigned short ld16(const void* p, int i, bool isbf){
    return isbf ? ((const unsigned short*)p)[i] : f2b(((const float*)p)[i]);
}
DEV float sigm(float x){ return 1.f / (1.f + __expf(-x)); }

struct WPtrs {
    const void *ptW1, *ptb1, *ptW2, *ptb2;
    const void *pfW1, *pfb1, *pfW2, *pfb2;
    const void *zkW, *zkb, *rkW, *rkb, *cW, *cb;
    const void *eW1, *eb1, *eW2, *eb2;
    const void *dW1, *db1, *dW2, *db2;
};

// ---- dtype detection ----
__global__ __launch_bounds__(256) void detect_kernel(const void* y, float* __restrict__ ws){
    __shared__ int bad;
    if (threadIdx.x == 0) bad = 0;
    __syncthreads();
    const unsigned short* yy = (const unsigned short*)y;
    int mybad = 0;
    for (int i = threadIdx.x; i < 4096; i += 256){
        float v = b2f(yy[i]);
        if (!(v > -1.0e6f && v < 1.0e6f)) mybad = 1;
    }
    if (mybad) bad = 1;
    __syncthreads();
    if (threadIdx.x == 0) ws[FLAG_OFF] = bad ? 0.0f : 1.0f;
}

// ---- weight prep ----
__global__ __launch_bounds__(256) void prep_kernel(WPtrs P, float* __restrict__ ws){
    int j = blockIdx.x * 256 + threadIdx.x;
    if (j >= PREP_TOTAL) return;
    bool isbf = ws[FLAG_OFF] > 0.5f;
    if (j < 24832){
        int k = j >> 7, c = j & 127;
        ws[WZR_OFF+j] = (c < 64) ? ldv(P.zkW, k*64+c, isbf) : ldv(P.rkW, k*64+(c-64), isbf);
        return;
    } j -= 24832;
    if (j < 128){ ws[GB_OFF+j] = (j < 64) ? ldv(P.zkb, j, isbf) : ldv(P.rkb, j-64, isbf); return; } j -= 128;
    if (j < 12416){ ws[CW_OFF+j] = ldv(P.cW, j, isbf); return; } j -= 12416;
    if (j < 64){ ws[CB_OFF+j] = ldv(P.cb, j, isbf); return; } j -= 64;
    if (j < 8192){ ws[PT1_OFF+j] = ldv(P.ptW1, j, isbf); return; } j -= 8192;
    if (j < 192){ ws[AT_OFF+j] = ldv(P.ptW1, 128*64+j, isbf); return; } j -= 192;
    if (j < 64){ ws[BT1_OFF+j] = ldv(P.ptb1, j, isbf); return; } j -= 64;
    if (j < 4096){ ws[WT2_OFF+j] = ldv(P.ptW2, j, isbf); return; } j -= 4096;
    if (j < 64){ ws[BT2_OFF+j] = ldv(P.ptb2, j, isbf); return; } j -= 64;
    if (j < 8192){ ws[PF1_OFF+j] = ldv(P.pfW1, j, isbf); return; } j -= 8192;
    if (j < 192){ ws[AF_OFF+j] = ldv(P.pfW1, 128*64+j, isbf); return; } j -= 192;
    if (j < 64){ ws[BF1_OFF+j] = ldv(P.pfb1, j, isbf); return; } j -= 64;
    if (j < 4096){ ws[WF2_OFF+j] = ldv(P.pfW2, j, isbf); return; } j -= 4096;
    if (j < 64){ ws[BF2_OFF+j] = ldv(P.pfb2, j, isbf); return; } j -= 64;
    if (j < 4096){ ws[DW1_OFF+j] = ldv(P.dW1, j, isbf); return; } j -= 4096;
    if (j < 64){ ws[DW2_OFF+j] = ldv(P.dW2, j, isbf); return; } j -= 64;
    if (j < 64){ ws[DB1_OFF+j] = ldv(P.db1, j, isbf); return; } j -= 64;
    if (j < 1){ ws[DB2_OFF] = ldv(P.db2, 0, isbf); return; } j -= 1;
    if (j < 64){ ws[EW1_OFF+j] = ldv(P.eW1, j, isbf); return; } j -= 64;
    if (j < 64){ ws[EB1_OFF+j] = ldv(P.eb1, j, isbf); return; } j -= 64;
    if (j < 4096){ ws[EW2_OFF+j] = ldv(P.eW2, j, isbf); return; } j -= 4096;
    if (j < 64){ ws[EB2_OFF+j] = ldv(P.eb2, j, isbf); return; } j -= 64;
    ws[LOSS_OFF+j] = 0.f;
}

__global__ __launch_bounds__(256) void prb_split(const void* __restrict__ prb, float* __restrict__ ws){
    int i = blockIdx.x * 256 + threadIdx.x;
    if (i >= N) return;
    bool isbf = ws[FLAG_OFF] > 0.5f;
    ws[PRB0_OFF+i] = ldv(prb, 2*i,   isbf);
    ws[PRB1_OFF+i] = ldv(prb, 2*i+1, isbf);
}

// ---- CSR build ----
__global__ __launch_bounds__(256) void zero_deg(int* __restrict__ wsI){
    int i = blockIdx.x * 256 + threadIdx.x;
    if (i < N){ wsI[CDEG_OFF+i] = 0; wsI[RDEG_OFF+i] = 0; wsI[SDEG_OFF+i] = 0; }
}
__global__ __launch_bounds__(256) void hist_kernel(const int* __restrict__ ei, int* __restrict__ wsI){
    int e = blockIdx.x * 256 + threadIdx.x;
    if (e >= E) return;
    int r = ei[e], c = ei[E+e];
    atomicAdd(&wsI[RDEG_OFF + r], 1);
    atomicAdd(&wsI[CDEG_OFF + c], 1);
    if (r == c) atomicAdd(&wsI[SDEG_OFF + r], 1);
}
DEV int deg_at(const int* wsI, int y, int i){
    if (y == 0) return wsI[CDEG_OFF+i] - wsI[SDEG_OFF+i];
    if (y == 1) return wsI[RDEG_OFF+i] - wsI[SDEG_OFF+i];
    return wsI[RDEG_OFF+i];
}
__global__ __launch_bounds__(256) void scan1(int* __restrict__ wsI){
    int y = blockIdx.y;
    int* tmp = wsI + (y == 0 ? LCP_OFF : (y == 1 ? LRP_OFF : FRP_OFF));
    int i = blockIdx.x * 256 + threadIdx.x;
    __shared__ int sh[256];
    int v = (i < N) ? deg_at(wsI, y, i) : 0;
    sh[threadIdx.x] = v;
    __syncthreads();
    #pragma unroll
    for (int off = 1; off < 256; off <<= 1){
        int t = (threadIdx.x >= (unsigned)off) ? sh[threadIdx.x - off] : 0;
        __syncthreads();
        sh[threadIdx.x] += t;
        __syncthreads();
    }
    if (i < N) tmp[i] = sh[threadIdx.x] - v;
    if (threadIdx.x == 255) wsI[BS_OFF + y*256 + blockIdx.x] = sh[255];
}
__global__ __launch_bounds__(256) void scan2(int* __restrict__ wsI){
    int y = blockIdx.y, t = threadIdx.x;
    __shared__ int sh[256];
    int v = (t < 196) ? wsI[BS_OFF + y*256 + t] : 0;
    sh[t] = v;
    __syncthreads();
    #pragma unroll
    for (int off = 1; off < 256; off <<= 1){
        int u = (t >= (unsigned)off) ? sh[t - off] : 0;
        __syncthreads();
        sh[t] += u;
        __syncthreads();
    }
    wsI[BO_OFF + y*256 + t] = sh[t] - v;
}
__global__ __launch_bounds__(256) void scan3(int* __restrict__ wsI){
    int y = blockIdx.y;
    int* ptr  = wsI + (y == 0 ? LCP_OFF : (y == 1 ? LRP_OFF : FRP_OFF));
    int* fill = wsI + (y == 0 ? LCF_OFF : (y == 1 ? LRF_OFF : FRF_OFF));
    int i = blockIdx.x * 256 + threadIdx.x;
    if (i < N){
        int d = deg_at(wsI, y, i);
        int p = ptr[i] + wsI[BO_OFF + y*256 + blockIdx.x];
        ptr[i] = p; fill[i] = p;
        if (i == N-1) ptr[N] = p + d;
    }
}
// scatter directly writes final CSR-ordered records (no staging, no reorder)
__global__ __launch_bounds__(256) void scatter_build(const int* __restrict__ ei,
                                                     const void* __restrict__ attr,
                                                     const void* __restrict__ aij,
                                                     float* __restrict__ ws){
    int e = blockIdx.x * 256 + threadIdx.x;
    if (e >= E) return;
    int* wsI = (int*)ws;
    bool isbf = ws[FLAG_OFF] > 0.5f;
    int r = ei[e], c = ei[E+e];
    unsigned a0 = ld16(attr, 3*e, isbf), a1 = ld16(attr, 3*e+1, isbf);
    unsigned a2 = ld16(attr, 3*e+2, isbf), av = ld16(aij, e, isbf);
    unsigned a01 = a0 | (a1 << 16);
    int p3 = atomicAdd(&wsI[FRF_OFF + r], 1);
    ((unsigned*)(ws + AREC_OFF))[p3] = (unsigned)c | (av << 16);
    if (r != c){
        int p1 = atomicAdd(&wsI[LCF_OFF + c], 1);
        ((uint2*)(ws + CREC_OFF))[p1] = make_uint2((unsigned)r | (a2 << 16), a01);
        int p2 = atomicAdd(&wsI[LRF_OFF + r], 1);
        ((uint2*)(ws + RREC_OFF))[p2] = make_uint2((unsigned)c | (a2 << 16), a01);
    }
}

// ---- encoder ----
__global__ __launch_bounds__(256) void encode_init(const void* __restrict__ x,
                                                   float* __restrict__ ws){
    int node = blockIdx.x * 256 + threadIdx.x;
    if (node >= N) return;
    bool isbf = ws[FLAG_OFF] > 0.5f;
    int j0 = blockIdx.y * 32;
    float xv = ldv(x, node, isbf);
    float acc[32];
    #pragma unroll
    for (int j = 0; j < 32; j++) acc[j] = ws[EB2_OFF + j0 + j];
    for (int k = 0; k < 64; k++){
        float t = fmaxf(fmaf(xv, ws[EW1_OFF+k], ws[EB1_OFF+k]), 0.f);
        const float* wr = ws + EW2_OFF + (size_t)k*64 + j0;
        #pragma unroll
        for (int j = 0; j < 32; j++) acc[j] = fmaf(t, wr[j], acc[j]);
    }
    #pragma unroll
    for (int j = 0; j < 32; j++){
        ws[H0F_OFF + (size_t)(j0+j)*N + node] = acc[j];
        ws[HF_OFF  + (size_t)(j0+j)*N + node] = acc[j];
    }
}

// ---- per-direction first-layer precompute ----
__global__ __launch_bounds__(256) void node_pre(float* __restrict__ ws){
    int idx = blockIdx.x * 256 + threadIdx.x;
    if (idx >= N*64) return;
    int dir = blockIdx.y;
    int node = idx >> 6, f = idx & 63;
    const float* W1 = ws + (dir ? PF1_OFF : PT1_OFF);
    float* paOut = ws + (dir ? PAF_OFF : PAT_OFF);
    unsigned short* pbOut = (unsigned short*)(ws + (dir ? PBF_OFF : PBT_OFF));
    float aA = 0.f, aB = 0.f;
    for (int k = 0; k < 64; k++){
        float hv = ws[HF_OFF + (size_t)k*N + node];
        aA = fmaf(hv, W1[k*64+f],      aA);
        aB = fmaf(hv, W1[(64+k)*64+f], aB);
    }
    paOut[idx] = aA;
    pbOut[idx] = f2b(aB);
}

// ---- CSR message gather: wave/node, lane=feature; filtered CSR, 8B records ----
__global__ __launch_bounds__(256) void gather_msgs(float* __restrict__ ws){
    __shared__ float sW2[4096];
    int dir = blockIdx.y;
    {
        const float* W2 = ws + (dir ? WF2_OFF : WT2_OFF);
        for (int i = threadIdx.x; i < 4096; i += 256) sW2[i] = W2[i];
    }
    __syncthreads();
    const int* wsI = (const int*)ws;
    const int* csrPtr = wsI + (dir ? LRP_OFF : LCP_OFF);
    const uint2* rec = (const uint2*)(ws + (dir ? RREC_OFF : CREC_OFF));
    float* pa = ws + (dir ? PAF_OFF : PAT_OFF);
    const unsigned short* pgb = (const unsigned short*)(ws + (dir ? PBF_OFF : PBT_OFF));
    const float* A3 = ws + (dir ? AF_OFF : AT_OFF);
    const float* b1 = ws + (dir ? BF1_OFF : BT1_OFF);
    const float* b2 = ws + (dir ? BF2_OFF : BT2_OFF);

    int lane = threadIdx.x & 63;
    int wv = threadIdx.x >> 6;
    float A0 = A3[lane], A1 = A3[64+lane], A2 = A3[128+lane];
    float B1 = b1[lane], B2 = b2[lane];
    int gw = blockIdx.x * 4 + wv;
    int nw = gridDim.x * 4;
    for (int node = gw; node < N; node += nw){
        float pav = pa[(size_t)node*64 + lane] + B1;
        float hs = 0.f;
        int beg = csrPtr[node], end = csrPtr[node+1];
        int cnt = end - beg;
        for (int base = beg; base < end; base += 64){
            int mcnt = end - base; if (mcnt > 64) mcnt = 64;
            unsigned rxL = 0, ryL = 0;
            if (lane < mcnt){
                uint2 q = rec[base + lane];
                rxL = q.x; ryL = q.y;
            }
            for (int g = 0; g < mcnt; g += 8){
                unsigned rxa[8], rya[8];
                float pb[8];
                #pragma unroll
                for (int t = 0; t < 8; t++){
                    rxa[t] = (unsigned)bcasti((int)rxL, g+t);
                    rya[t] = (unsigned)bcasti((int)ryL, g+t);
                    int o = (int)(rxa[t] & 0xffffu);
                    float pv = b2f(pgb[(size_t)o*64 + lane]);
                    pb[t] = (g+t < mcnt) ? pv : -3.0e38f;
                }
                #pragma unroll
                for (int t = 0; t < 8; t++){
                    float hv = fmaf(blo(rya[t]), A0,
                               fmaf(bhi(rya[t]), A1,
                               fmaf(bhi(rxa[t]), A2, pav))) + pb[t];
                    hs += fmaxf(hv, 0.f);
                }
            }
        }
        float m = (float)cnt * B2;
        #pragma unroll
        for (int k = 0; k < 64; k++) m = fmaf(bcastf(hs, k), sW2[k*64+lane], m);
        pa[(size_t)node*64 + lane] = m;
    }
}

// ---- transpose msg [node][64] f32 -> [64][N] bf16 ----
__global__ __launch_bounds__(256) void transpose_msg(float* __restrict__ ws){
    __shared__ float t[64][65];
    const float* src = ws + (blockIdx.y ? PAF_OFF : PAT_OFF);
    unsigned short* dst = (unsigned short*)(ws + (blockIdx.y ? MFF_OFF : MTF_OFF));
    int n0 = blockIdx.x * 64;
    #pragma unroll
    for (int i = 0; i < 16; i++){
        int idx = i*256 + threadIdx.x;
        int nl = idx >> 6, f = idx & 63;
        int node = n0 + nl;
        t[nl][f] = (node < N) ? src[(size_t)node*64 + f] : 0.f;
    }
    __syncthreads();
    #pragma unroll
    for (int i = 0; i < 16; i++){
        int idx = i*256 + threadIdx.x;
        int fw = idx >> 6, nl = idx & 63;
        int node = n0 + nl;
        if (node < N) dst[(size_t)fw*N + node] = f2b(t[nl][fw]);
    }
}

// ---- gate z/r ----
__global__ __launch_bounds__(256) void gate_zr(float* __restrict__ ws){
    int node = blockIdx.x * 256 + threadIdx.x;
    if (node >= N) return;
    int ch = blockIdx.y >> 1, tl = blockIdx.y & 1;
    const float* W = ws + WZR_OFF + ch*64 + tl*32;
    const unsigned short* mtU = (const unsigned short*)(ws + MTF_OFF);
    const unsigned short* mfU = (const unsigned short*)(ws + MFF_OFF);
    float p0 = ws[PRB0_OFF+node], p1 = ws[PRB1_OFF+node];
    float acc[32];
    #pragma unroll
    for (int j = 0; j < 32; j++)
        acc[j] = ws[GB_OFF + ch*64 + tl*32 + j] + p0*W[192*128+j] + p1*W[193*128+j];
    for (int k = 0; k < 64; k++){
        float a = ws[HF_OFF + (size_t)k*N + node];
        const float* wr = W + (size_t)k*128;
        #pragma unroll
        for (int j = 0; j < 32; j++) acc[j] = fmaf(a, wr[j], acc[j]);
    }
    for (int k = 0; k < 64; k++){
        float a = b2f(mtU[(size_t)k*N + node]);
        const float* wr = W + (size_t)(64+k)*128;
        #pragma unroll
        for (int j = 0; j < 32; j++) acc[j] = fmaf(a, wr[j], acc[j]);
    }
    for (int k = 0; k < 64; k++){
        float a = b2f(mfU[(size_t)k*N + node]);
        const float* wr = W + (size_t)(128+k)*128;
        #pragma unroll
        for (int j = 0; j < 32; j++) acc[j] = fmaf(a, wr[j], acc[j]);
    }
    if (ch == 0){
        #pragma unroll
        for (int j = 0; j < 32; j++)
            ws[AL_OFF + (size_t)(tl*32+j)*N + node] = sigm(acc[j]);
    } else {
        #pragma unroll
        for (int j = 0; j < 32; j++){
            int row = tl*32+j;
            ws[RH_OFF + (size_t)row*N + node] = sigm(acc[j]) * ws[HF_OFF + (size_t)row*N + node];
        }
    }
}

// ---- gate corr + state update ----
__global__ __launch_bounds__(256) void gate_corr(const int* __restrict__ tags,
                                                 float* __restrict__ ws){
    int node = blockIdx.x * 256 + threadIdx.x;
    if (node >= N) return;
    int tl = blockIdx.y, j0 = tl*32;
    const float* W = ws + CW_OFF + j0;
    const unsigned short* mtU = (const unsigned short*)(ws + MTF_OFF);
    const unsigned short* mfU = (const unsigned short*)(ws + MFF_OFF);
    float p0 = ws[PRB0_OFF+node], p1 = ws[PRB1_OFF+node];
    float acc[32];
    #pragma unroll
    for (int j = 0; j < 32; j++)
        acc[j] = ws[CB_OFF + j0 + j] + p0*W[192*64+j] + p1*W[193*64+j];
    for (int k = 0; k < 64; k++){
        float a = ws[RH_OFF + (size_t)k*N + node];
        const float* wr = W + (size_t)k*64;
        #pragma unroll
        for (int j = 0; j < 32; j++) acc[j] = fmaf(a, wr[j], acc[j]);
    }
    for (int k = 0; k < 64; k++){
        float a = b2f(mtU[(size_t)k*N + node]);
        const float* wr = W + (size_t)(64+k)*64;
        #pragma unroll
        for (int j = 0; j < 32; j++) acc[j] = fmaf(a, wr[j], acc[j]);
    }
    for (int k = 0; k < 64; k++){
        float a = b2f(mfU[(size_t)k*N + node]);
        const float* wr = W + (size_t)(128+k)*64;
        #pragma unroll
        for (int j = 0; j < 32; j++) acc[j] = fmaf(a, wr[j], acc[j]);
    }
    int tg = tags[node];
    #pragma unroll
    for (int j = 0; j < 32; j++){
        size_t off = (size_t)(j0+j)*N + node;
        float hn = fmaf(ws[AL_OFF+off], tanhf(acc[j]), ws[HF_OFF+off]);
        if (tg == 1) hn = ws[H0F_OFF+off];
        ws[HF_OFF+off] = hn;
    }
}

// ---- decode stage 1 ----
__global__ __launch_bounds__(256) void dec1(const float* __restrict__ src,
                                            float* __restrict__ dst,
                                            float* __restrict__ ws){
    int node = blockIdx.x * 256 + threadIdx.x;
    if (node >= N) return;
    int j0 = blockIdx.y * 32;
    float acc[32];
    #pragma unroll
    for (int j = 0; j < 32; j++) acc[j] = ws[DB1_OFF + j0 + j];
    for (int k = 0; k < 64; k++){
        float a = src[(size_t)k*N + node];
        const float* wr = ws + DW1_OFF + (size_t)k*64 + j0;
        #pragma unroll
        for (int j = 0; j < 32; j++) acc[j] = fmaf(a, wr[j], acc[j]);
    }
    #pragma unroll
    for (int j = 0; j < 32; j++)
        dst[(size_t)(j0+j)*N + node] = fmaxf(acc[j], 0.f);
}

// ---- decode stage 2 + encode(u) + enc loss ----
__global__ __launch_bounds__(256) void enc_u(int step, float* __restrict__ ws){
    int node = blockIdx.x * 256 + threadIdx.x;
    float encA = 0.f;
    if (node < N){
        int j0 = blockIdx.y * 32;
        float u = ws[DB2_OFF];
        for (int j = 0; j < 64; j++)
            u = fmaf(ws[T1_OFF + (size_t)j*N + node], ws[DW2_OFF+j], u);
        if (blockIdx.y == 0) ws[UV_OFF+node] = u;
        float acc[32];
        #pragma unroll
        for (int j = 0; j < 32; j++) acc[j] = ws[EB2_OFF + j0 + j];
        for (int k = 0; k < 64; k++){
            float t = fmaxf(fmaf(u, ws[EW1_OFF+k], ws[EB1_OFF+k]), 0.f);
            const float* wr = ws + EW2_OFF + (size_t)k*64 + j0;
            #pragma unroll
            for (int j = 0; j < 32; j++) acc[j] = fmaf(t, wr[j], acc[j]);
        }
        #pragma unroll
        for (int j = 0; j < 32; j++){
            size_t off = (size_t)(j0+j)*N + node;
            ws[EV_OFF+off] = acc[j];
            float d = acc[j] - ws[HF_OFF+off];
            encA += d*d;
        }
    }
    encA = wave_sum(encA);
    if ((threadIdx.x & 63) == 0) atomicAdd(&ws[LOSS_OFF + step*3 + 1], encA);
}

// ---- final: u2 = dec(E), auto loss, residual (4B records), res loss ----
__global__ __launch_bounds__(256) void aux_res(int step, const void* __restrict__ y,
                                               float* __restrict__ ws){
    const int* wsI = (const int*)ws;
    int node = blockIdx.x * 256 + threadIdx.x;
    bool isbf = ws[FLAG_OFF] > 0.5f;
    float autoA = 0.f, resA = 0.f;
    if (node < N){
        float u2 = ws[DB2_OFF];
        for (int j = 0; j < 64; j++)
            u2 = fmaf(ws[T1_OFF + (size_t)j*N + node], ws[DW2_OFF+j], u2);
        float u = ws[UV_OFF+node];
        float ad = u2 - u;
        autoA = ad*ad;
        float acc = 0.f;
        int beg = wsI[FRP_OFF+node], end = wsI[FRP_OFF+node+1];
        const unsigned* arec = (const unsigned*)(ws + AREC_OFF);
        for (int p = beg; p < end; p++){
            unsigned rc = arec[p];
            acc = fmaf(bhi(rc), ws[UV_OFF + (int)(rc & 0xffffu)], acc);
        }
        float d = acc - ldv(y, node, isbf);
        resA = d*d;
    }
    autoA = wave_sum(autoA);
    resA = wave_sum(resA);
    if ((threadIdx.x & 63) == 0){
        atomicAdd(&ws[LOSS_OFF + step*3 + 2], autoA);
        atomicAdd(&ws[LOSS_OFF + step*3], resA);
    }
}

// ---- output writer ----
__global__ __launch_bounds__(256) void write_out(void* __restrict__ outp,
                                                 const float* __restrict__ ws){
    int i = blockIdx.x * 256 + threadIdx.x;
    if (i > N) return;
    bool isbf = ws[FLAG_OFF] > 0.5f;
    float v;
    if (i < N){
        v = ws[UV_OFF+i];
    } else {
        const float* L = ws + LOSS_OFF;
        float inv = 1.f / (float)N, invl = 1.f / ((float)N * 64.f);
        v = 0.9f*L[0]*inv + L[1]*invl + L[2]*inv
          +      L[3]*inv + L[4]*invl + L[5]*inv;
    }
    if (isbf) ((unsigned short*)outp)[i] = f2b(v);
    else      ((float*)outp)[i] = v;
}

extern "C" void kernel_launch(void* const* d_in, const int* in_sizes, int n_in,
                              void* d_out, int out_size, void* d_ws, size_t ws_size,
                              hipStream_t stream){
    const void* x    = d_in[0];
    const void* y    = d_in[2];
    const int* tags  = (const int*)d_in[3];
    const int* ei    = (const int*)d_in[4];
    const void* attr = d_in[5];
    const void* aij  = d_in[6];
    const void* prb  = d_in[7];
    WPtrs P;
    P.ptW1 = d_in[8];  P.ptb1 = d_in[9];  P.ptW2 = d_in[10]; P.ptb2 = d_in[11];
    P.pfW1 = d_in[12]; P.pfb1 = d_in[13]; P.pfW2 = d_in[14]; P.pfb2 = d_in[15];
    P.zkW  = d_in[16]; P.zkb  = d_in[17]; P.rkW  = d_in[18]; P.rkb  = d_in[19];
    P.cW   = d_in[20]; P.cb   = d_in[21];
    P.eW1  = d_in[22]; P.eb1  = d_in[23]; P.eW2  = d_in[24]; P.eb2  = d_in[25];
    P.dW1  = d_in[26]; P.db1  = d_in[27]; P.dW2  = d_in[28]; P.db2  = d_in[29];
    float* ws = (float*)d_ws;
    int* wsI = (int*)d_ws;

    detect_kernel<<<1, 256, 0, stream>>>(y, ws);
    prep_kernel<<<(PREP_TOTAL + 255)/256, 256, 0, stream>>>(P, ws);
    prb_split<<<196, 256, 0, stream>>>(prb, ws);
    zero_deg<<<196, 256, 0, stream>>>(wsI);
    hist_kernel<<<E/256, 256, 0, stream>>>(ei, wsI);
    scan1<<<dim3(196, 3), 256, 0, stream>>>(wsI);
    scan2<<<dim3(1, 3), 256, 0, stream>>>(wsI);
    scan3<<<dim3(196, 3), 256, 0, stream>>>(wsI);
    scatter_build<<<E/256, 256, 0, stream>>>(ei, attr, aij, ws);
    encode_init<<<dim3(196, 2), 256, 0, stream>>>(x, ws);
    for (int step = 0; step < 2; step++){
        node_pre<<<dim3((N*64)/256, 2), 256, 0, stream>>>(ws);
        gather_msgs<<<dim3(2048, 2), 256, 0, stream>>>(ws);
        transpose_msg<<<dim3(782, 2), 256, 0, stream>>>(ws);
        gate_zr<<<dim3(196, 4), 256, 0, stream>>>(ws);
        gate_corr<<<dim3(196, 2), 256, 0, stream>>>(tags, ws);
        dec1<<<dim3(196, 2), 256, 0, stream>>>(ws + HF_OFF, ws + T1_OFF, ws);
        enc_u<<<dim3(196, 2), 256, 0, stream>>>(step, ws);
        dec1<<<dim3(196, 2), 256, 0, stream>>>(ws + EV_OFF, ws + T1_OFF, ws);
        aux_res<<<196, 256, 0, stream>>>(step, y, ws);
    }
    write_out<<<197, 256, 0, stream>>>(d_out, ws);
}